// Round 1
// baseline (1033.142 us; speedup 1.0000x reference)
//
#include <hip/hip_runtime.h>
#include <hip/hip_bf16.h>
#include <cstddef>

#define DMODEL 1024
#define DI     2048
#define DS     16
#define LSEQ   2048
#define BATCH  2
#define NC     32            // number of scan chunks
#define TCH    (LSEQ / NC)   // 64 steps per chunk

// ---------------------------------------------------------------------------
// fp32 tiled GEMM, "NT" form: C[m,n] = sum_k A[m*K+k] * Bm[n*K+k]
// (both operands row-major with K contiguous — matches x@W.T everywhere here)
// ---------------------------------------------------------------------------
template <int BM, int BN, int BK>
__global__ void gemm_nt(const float* __restrict__ A, const float* __restrict__ Bm,
                        float* __restrict__ C, int M, int N, int K) {
    __shared__ float As[BK][BM + 4];
    __shared__ float Bs[BK][BN + 4];

    const int tx = threadIdx.x;          // 0..15 -> n
    const int ty = threadIdx.y;          // 0..15 -> m
    const int tid = ty * 16 + tx;        // 0..255
    const int m0 = blockIdx.y * BM;
    const int n0 = blockIdx.x * BN;

    float acc[4][4] = {};

    const int lr = tid >> 2;             // 0..63 : tile row
    const int lk = (tid & 3) * 4;        // 0,4,8,12 : k chunk

    for (int k0 = 0; k0 < K; k0 += BK) {
        // load A tile (BM x BK) and B tile (BN x BK), float4 per thread
        float4 av = *reinterpret_cast<const float4*>(&A[(size_t)(m0 + lr) * K + k0 + lk]);
        float4 bv = *reinterpret_cast<const float4*>(&Bm[(size_t)(n0 + lr) * K + k0 + lk]);
        As[lk + 0][lr] = av.x; As[lk + 1][lr] = av.y; As[lk + 2][lr] = av.z; As[lk + 3][lr] = av.w;
        Bs[lk + 0][lr] = bv.x; Bs[lk + 1][lr] = bv.y; Bs[lk + 2][lr] = bv.z; Bs[lk + 3][lr] = bv.w;
        __syncthreads();

        #pragma unroll
        for (int kk = 0; kk < BK; ++kk) {
            float4 ra = *reinterpret_cast<const float4*>(&As[kk][ty * 4]);
            float4 rb = *reinterpret_cast<const float4*>(&Bs[kk][tx * 4]);
            float a[4] = {ra.x, ra.y, ra.z, ra.w};
            float b[4] = {rb.x, rb.y, rb.z, rb.w};
            #pragma unroll
            for (int i = 0; i < 4; ++i)
                #pragma unroll
                for (int j = 0; j < 4; ++j)
                    acc[i][j] += a[i] * b[j];
        }
        __syncthreads();
    }

    #pragma unroll
    for (int i = 0; i < 4; ++i) {
        float4 v = {acc[i][0], acc[i][1], acc[i][2], acc[i][3]};
        *reinterpret_cast<float4*>(&C[(size_t)(m0 + ty * 4 + i) * N + n0 + tx * 4]) = v;
    }
}

// ---------------------------------------------------------------------------
// depthwise causal conv (width 4) + bias + SiLU on the x_ssm half of xz
// ---------------------------------------------------------------------------
__global__ void conv_silu(const float* __restrict__ xz, const float* __restrict__ cw,
                          const float* __restrict__ cb, float* __restrict__ xact) {
    int idx = blockIdx.x * 256 + threadIdx.x;   // flat over B*L*DI
    if (idx >= BATCH * LSEQ * DI) return;
    int d = idx % DI;
    int l = (idx / DI) % LSEQ;
    int b = idx / (DI * LSEQ);

    float acc = cb[d];
    #pragma unroll
    for (int j = 0; j < 4; ++j) {
        int ls = l - 3 + j;
        if (ls >= 0)
            acc += xz[((size_t)(b * LSEQ + ls)) * (2 * DI) + d] * cw[d * 4 + j];
    }
    xact[idx] = acc / (1.f + __expf(-acc));
}

// ---------------------------------------------------------------------------
// skinny GEMM: proj[row, n] = dot(xact[row,:], W_x[n,:]) ; row-stride padded 36
// ---------------------------------------------------------------------------
__global__ void gemm_proj(const float* __restrict__ xact, const float* __restrict__ Wx,
                          float* __restrict__ proj) {
    int row = blockIdx.x;        // 0..B*L-1
    int n = threadIdx.x;         // 64 lanes, 33 active
    if (n >= 33) return;
    const float* xr = xact + (size_t)row * DI;
    const float* wr = Wx + (size_t)n * DI;
    float acc = 0.f;
    for (int k = 0; k < DI; k += 4) {
        float4 xv = *reinterpret_cast<const float4*>(xr + k);
        float4 wv = *reinterpret_cast<const float4*>(wr + k);
        acc += xv.x * wv.x + xv.y * wv.y + xv.z * wv.z + xv.w * wv.w;
    }
    proj[(size_t)row * 36 + n] = acc;
}

__device__ __forceinline__ float softplus_f(float v) {
    return (v > 20.f) ? v : log1pf(__expf(v));
}

// ---------------------------------------------------------------------------
// scan phase 1: per chunk per channel, P = prod(dA), Hend = local scan end
// layout of P/H/Hin: [b][c][n][d]
// ---------------------------------------------------------------------------
__global__ void scan_phase1(const float* __restrict__ xact, const float* __restrict__ proj,
                            const float* __restrict__ A_log, const float* __restrict__ W_dt,
                            const float* __restrict__ b_dt,
                            float* __restrict__ Pout, float* __restrict__ Hout) {
    const int d = blockIdx.x * 256 + threadIdx.x;
    const int c = blockIdx.y;
    const int b = blockIdx.z;

    float A[DS], h[DS], P[DS];
    #pragma unroll
    for (int n = 0; n < DS; ++n) {
        A[n] = -__expf(A_log[d * DS + n]);
        h[n] = 0.f;
        P[n] = 1.f;
    }
    const float wdt = W_dt[d], bdt = b_dt[d];

    const int l0 = c * TCH;
    for (int l = l0; l < l0 + TCH; ++l) {
        const float* pr = proj + (size_t)(b * LSEQ + l) * 36;
        float dt = softplus_f(pr[32] * wdt + bdt);
        float x = xact[((size_t)(b * LSEQ + l)) * DI + d];
        float xdt = x * dt;
        #pragma unroll
        for (int n = 0; n < DS; ++n) {
            float dA = __expf(dt * A[n]);
            h[n] = dA * h[n] + xdt * pr[n];
            P[n] *= dA;
        }
    }
    size_t base = ((size_t)(b * NC + c) * DS) * DI + d;
    #pragma unroll
    for (int n = 0; n < DS; ++n) {
        Pout[base + (size_t)n * DI] = P[n];
        Hout[base + (size_t)n * DI] = h[n];
    }
}

// ---------------------------------------------------------------------------
// scan phase 2: sequential combine over chunks (tiny): Hin[c] = state before c
// ---------------------------------------------------------------------------
__global__ void scan_phase2(const float* __restrict__ P, const float* __restrict__ H,
                            float* __restrict__ Hin) {
    int idx = blockIdx.x * 256 + threadIdx.x;   // b*DS*DI + n*DI + d
    int b = idx / (DS * DI);
    int nd = idx % (DS * DI);
    float h = 0.f;
    for (int c = 0; c < NC; ++c) {
        size_t off = ((size_t)(b * NC + c) * DS * DI) + nd;
        Hin[off] = h;
        h = P[off] * h + H[off];
    }
}

// ---------------------------------------------------------------------------
// scan phase 3: full per-chunk scan with correct incoming state; fuse
// y = (scan_y + x*D) * silu(z); writes y in place over xact
// ---------------------------------------------------------------------------
__global__ void scan_phase3(float* __restrict__ xact_y, const float* __restrict__ xz,
                            const float* __restrict__ proj, const float* __restrict__ A_log,
                            const float* __restrict__ W_dt, const float* __restrict__ b_dt,
                            const float* __restrict__ Dp, const float* __restrict__ Hin) {
    const int d = blockIdx.x * 256 + threadIdx.x;
    const int c = blockIdx.y;
    const int b = blockIdx.z;

    float A[DS], h[DS];
    #pragma unroll
    for (int n = 0; n < DS; ++n) A[n] = -__expf(A_log[d * DS + n]);

    size_t hbase = ((size_t)(b * NC + c) * DS) * DI + d;
    #pragma unroll
    for (int n = 0; n < DS; ++n) h[n] = Hin[hbase + (size_t)n * DI];

    const float wdt = W_dt[d], bdt = b_dt[d], dpar = Dp[d];

    const int l0 = c * TCH;
    for (int l = l0; l < l0 + TCH; ++l) {
        const float* pr = proj + (size_t)(b * LSEQ + l) * 36;
        float dt = softplus_f(pr[32] * wdt + bdt);
        size_t xi = ((size_t)(b * LSEQ + l)) * DI + d;
        float x = xact_y[xi];
        float xdt = x * dt;
        float y = 0.f;
        #pragma unroll
        for (int n = 0; n < DS; ++n) {
            float dA = __expf(dt * A[n]);
            h[n] = dA * h[n] + xdt * pr[n];
            y += h[n] * pr[16 + n];
        }
        y += x * dpar;
        float z = xz[((size_t)(b * LSEQ + l)) * (2 * DI) + DI + d];
        float sz = z / (1.f + __expf(-z));
        xact_y[xi] = y * sz;
    }
}

// ---------------------------------------------------------------------------
extern "C" void kernel_launch(void* const* d_in, const int* in_sizes, int n_in,
                              void* d_out, int out_size, void* d_ws, size_t ws_size,
                              hipStream_t stream) {
    const float* x      = (const float*)d_in[0];
    const float* W_in   = (const float*)d_in[1];
    const float* conv_w = (const float*)d_in[2];
    const float* conv_b = (const float*)d_in[3];
    const float* W_x    = (const float*)d_in[4];
    const float* A_log  = (const float*)d_in[5];
    const float* Dp     = (const float*)d_in[6];
    const float* W_dt   = (const float*)d_in[7];
    const float* b_dt   = (const float*)d_in[8];
    const float* W_out  = (const float*)d_in[9];
    float* out = (float*)d_out;

    char* ws = (char*)d_ws;
    // workspace layout (bytes)
    float* XZ   = (float*)(ws + 0);            // B*L*4096*4 = 64 MiB
    float* XACT = (float*)(ws + 67108864);     // B*L*2048*4 = 32 MiB (later holds y)
    float* PROJ = (float*)(ws + 100663296);    // B*L*36*4   ≈ 0.56 MiB
    float* Pbuf = (float*)(ws + 101253120);    // B*NC*16*2048*4 = 8 MiB
    float* Hbuf = (float*)(ws + 109641728);    // 8 MiB
    float* Hin  = (float*)(ws + 118030336);    // 8 MiB ; total ≈ 126.5 MiB

    const int M = BATCH * LSEQ;   // 4096

    // 1) xz = x @ W_in.T    (M x 4096, K=1024)
    gemm_nt<64, 64, 16><<<dim3(2 * DI / 64, M / 64), dim3(16, 16), 0, stream>>>(
        x, W_in, XZ, M, 2 * DI, DMODEL);

    // 2) depthwise conv + bias + SiLU -> XACT
    conv_silu<<<(BATCH * LSEQ * DI) / 256, 256, 0, stream>>>(XZ, conv_w, conv_b, XACT);

    // 3) proj = XACT @ W_x.T  (padded row stride 36)
    gemm_proj<<<M, 64, 0, stream>>>(XACT, W_x, PROJ);

    // 4-6) chunked selective scan
    scan_phase1<<<dim3(DI / 256, NC, BATCH), 256, 0, stream>>>(
        XACT, PROJ, A_log, W_dt, b_dt, Pbuf, Hbuf);
    scan_phase2<<<(BATCH * DS * DI) / 256, 256, 0, stream>>>(Pbuf, Hbuf, Hin);
    scan_phase3<<<dim3(DI / 256, NC, BATCH), 256, 0, stream>>>(
        XACT, XZ, PROJ, A_log, W_dt, b_dt, Dp, Hin);

    // 7) out = y @ W_out.T  (M x 1024, K=2048)
    gemm_nt<64, 64, 16><<<dim3(DMODEL / 64, M / 64), dim3(16, 16), 0, stream>>>(
        XACT, W_out, out, M, DMODEL, DI);
}

// Round 2
// 472.586 us; speedup vs baseline: 2.1861x; 2.1861x over previous
//
#include <hip/hip_runtime.h>
#include <hip/hip_bf16.h>
#include <cstddef>

#define DMODEL 1024
#define DI     2048
#define DS     16
#define LSEQ   2048
#define BATCH  2
#define NC     32            // number of scan chunks
#define TCH    (LSEQ / NC)   // 64 steps per chunk

typedef __attribute__((ext_vector_type(8))) short short8;
typedef __attribute__((ext_vector_type(4))) float f32x4;

__device__ __forceinline__ unsigned short f2bf(float f) {
    unsigned int u = __float_as_uint(f);
    unsigned int r = (u + 0x7fff + ((u >> 16) & 1)) >> 16;   // RNE
    return (unsigned short)r;
}

__device__ __forceinline__ void gload_lds16(const void* g, void* l) {
    __builtin_amdgcn_global_load_lds(
        (const __attribute__((address_space(1))) unsigned int*)g,
        (__attribute__((address_space(3))) unsigned int*)l, 16, 0, 0);
}

// ---------------------------------------------------------------------------
// f32 -> bf16 convert (vectorized, 8 elems/thread)
// ---------------------------------------------------------------------------
__global__ void cvt_bf16(const float* __restrict__ in, unsigned short* __restrict__ out, int n8) {
    int i = blockIdx.x * 256 + threadIdx.x;
    if (i >= n8) return;
    const float4* p = reinterpret_cast<const float4*>(in) + i * 2;
    float4 v0 = p[0], v1 = p[1];
    typedef __attribute__((ext_vector_type(8))) unsigned short us8;
    us8 o;
    o[0] = f2bf(v0.x); o[1] = f2bf(v0.y); o[2] = f2bf(v0.z); o[3] = f2bf(v0.w);
    o[4] = f2bf(v1.x); o[5] = f2bf(v1.y); o[6] = f2bf(v1.z); o[7] = f2bf(v1.w);
    *reinterpret_cast<us8*>(out + (size_t)i * 8) = o;
}

// ---------------------------------------------------------------------------
// bf16 MFMA GEMM (m97 structure): C[m,n] = sum_k A[m,k]*B[n,k], fp32 out.
// 128x128 tile, BK=32, 256 threads (4 waves, 2x2), 16x16x32 MFMA.
// ---------------------------------------------------------------------------
__global__ __launch_bounds__(256)
void gemm_bf16_nt(const unsigned short* __restrict__ A, const unsigned short* __restrict__ B,
                  float* __restrict__ C, int M, int N, int K) {
    __shared__ unsigned short As[128 * 32];
    __shared__ unsigned short Bs[128 * 32];

    const int tid = threadIdx.x;
    const int wv = tid >> 6, ln = tid & 63;
    const int m0 = blockIdx.y * 128, n0 = blockIdx.x * 128;
    const int wm = wv >> 1, wn = wv & 1;          // wave -> 64x64 quadrant

    f32x4 acc[4][4] = {};

    const int srow = ln >> 2;            // 0..15 within staging chunk
    const int scol = (ln & 3) * 8;       // k-element offset
    const int fr = ln & 15, fk = (ln >> 4) * 8;   // fragment row / k-offset

    for (int k0 = 0; k0 < K; k0 += 32) {
        #pragma unroll
        for (int c = 0; c < 2; ++c) {
            int ch = wv * 2 + c;                       // 0..7 : 16-row chunk
            const unsigned short* ga = A + (size_t)(m0 + ch * 16 + srow) * K + k0 + scol;
            gload_lds16(ga, &As[ch * 512]);
            const unsigned short* gb = B + (size_t)(n0 + ch * 16 + srow) * K + k0 + scol;
            gload_lds16(gb, &Bs[ch * 512]);
        }
        __syncthreads();

        short8 af[4], bf_[4];
        #pragma unroll
        for (int i = 0; i < 4; ++i) {
            af[i]  = *reinterpret_cast<const short8*>(&As[(wm * 64 + i * 16 + fr) * 32 + fk]);
            bf_[i] = *reinterpret_cast<const short8*>(&Bs[(wn * 64 + i * 16 + fr) * 32 + fk]);
        }
        #pragma unroll
        for (int i = 0; i < 4; ++i)
            #pragma unroll
            for (int j = 0; j < 4; ++j)
                acc[i][j] = __builtin_amdgcn_mfma_f32_16x16x32_bf16(af[i], bf_[j], acc[i][j], 0, 0, 0);
        __syncthreads();
    }

    const int cr = (ln >> 4) * 4, cc = ln & 15;
    #pragma unroll
    for (int i = 0; i < 4; ++i) {
        int row = m0 + wm * 64 + i * 16 + cr;
        #pragma unroll
        for (int j = 0; j < 4; ++j) {
            int col = n0 + wn * 64 + j * 16 + cc;
            #pragma unroll
            for (int r = 0; r < 4; ++r)
                C[(size_t)(row + r) * N + col] = acc[i][j][r];
        }
    }
}

// ---------------------------------------------------------------------------
// depthwise causal conv (width 4) + bias + SiLU on the x_ssm half of xz
// ---------------------------------------------------------------------------
__global__ void conv_silu(const float* __restrict__ xz, const float* __restrict__ cw,
                          const float* __restrict__ cb, float* __restrict__ xact) {
    int idx = blockIdx.x * 256 + threadIdx.x;   // flat over B*L*DI
    if (idx >= BATCH * LSEQ * DI) return;
    int d = idx % DI;
    int l = (idx / DI) % LSEQ;
    int b = idx / (DI * LSEQ);

    float acc = cb[d];
    #pragma unroll
    for (int j = 0; j < 4; ++j) {
        int ls = l - 3 + j;
        if (ls >= 0)
            acc += xz[((size_t)(b * LSEQ + ls)) * (2 * DI) + d] * cw[d * 4 + j];
    }
    xact[idx] = acc / (1.f + __expf(-acc));
}

// ---------------------------------------------------------------------------
// skinny GEMM: proj[row, n] = dot(xact[row,:], W_x[n,:]) ; row-stride padded 36
// ---------------------------------------------------------------------------
__global__ void gemm_proj(const float* __restrict__ xact, const float* __restrict__ Wx,
                          float* __restrict__ proj) {
    int row = blockIdx.x;        // 0..B*L-1
    int n = threadIdx.x;         // 64 lanes, 33 active
    if (n >= 33) return;
    const float* xr = xact + (size_t)row * DI;
    const float* wr = Wx + (size_t)n * DI;
    float acc = 0.f;
    for (int k = 0; k < DI; k += 4) {
        float4 xv = *reinterpret_cast<const float4*>(xr + k);
        float4 wv = *reinterpret_cast<const float4*>(wr + k);
        acc += xv.x * wv.x + xv.y * wv.y + xv.z * wv.z + xv.w * wv.w;
    }
    proj[(size_t)row * 36 + n] = acc;
}

__device__ __forceinline__ float softplus_f(float v) {
    return (v > 20.f) ? v : log1pf(__expf(v));
}

// ---------------------------------------------------------------------------
// scan phase 1: per chunk per channel, P = prod(dA), Hend = local scan end
// ---------------------------------------------------------------------------
__global__ void scan_phase1(const float* __restrict__ xact, const float* __restrict__ proj,
                            const float* __restrict__ A_log, const float* __restrict__ W_dt,
                            const float* __restrict__ b_dt,
                            float* __restrict__ Pout, float* __restrict__ Hout) {
    const int d = blockIdx.x * 256 + threadIdx.x;
    const int c = blockIdx.y;
    const int b = blockIdx.z;

    float A[DS], h[DS], P[DS];
    #pragma unroll
    for (int n = 0; n < DS; ++n) {
        A[n] = -__expf(A_log[d * DS + n]);
        h[n] = 0.f;
        P[n] = 1.f;
    }
    const float wdt = W_dt[d], bdt = b_dt[d];

    const int l0 = c * TCH;
    for (int l = l0; l < l0 + TCH; ++l) {
        const float* pr = proj + (size_t)(b * LSEQ + l) * 36;
        float dt = softplus_f(pr[32] * wdt + bdt);
        float x = xact[((size_t)(b * LSEQ + l)) * DI + d];
        float xdt = x * dt;
        #pragma unroll
        for (int n = 0; n < DS; ++n) {
            float dA = __expf(dt * A[n]);
            h[n] = dA * h[n] + xdt * pr[n];
            P[n] *= dA;
        }
    }
    size_t base = ((size_t)(b * NC + c) * DS) * DI + d;
    #pragma unroll
    for (int n = 0; n < DS; ++n) {
        Pout[base + (size_t)n * DI] = P[n];
        Hout[base + (size_t)n * DI] = h[n];
    }
}

// ---------------------------------------------------------------------------
// scan phase 2: sequential combine over chunks
// ---------------------------------------------------------------------------
__global__ void scan_phase2(const float* __restrict__ P, const float* __restrict__ H,
                            float* __restrict__ Hin) {
    int idx = blockIdx.x * 256 + threadIdx.x;   // b*DS*DI + n*DI + d
    int b = idx / (DS * DI);
    int nd = idx % (DS * DI);
    float h = 0.f;
    for (int c = 0; c < NC; ++c) {
        size_t off = ((size_t)(b * NC + c) * DS * DI) + nd;
        Hin[off] = h;
        h = P[off] * h + H[off];
    }
}

// ---------------------------------------------------------------------------
// scan phase 3: full per-chunk scan with correct incoming state; fuse
// y = (scan_y + x*D) * silu(z); writes y as bf16 for the output GEMM
// ---------------------------------------------------------------------------
__global__ void scan_phase3(const float* __restrict__ xact, const float* __restrict__ xz,
                            const float* __restrict__ proj, const float* __restrict__ A_log,
                            const float* __restrict__ W_dt, const float* __restrict__ b_dt,
                            const float* __restrict__ Dp, const float* __restrict__ Hin,
                            unsigned short* __restrict__ ybf) {
    const int d = blockIdx.x * 256 + threadIdx.x;
    const int c = blockIdx.y;
    const int b = blockIdx.z;

    float A[DS], h[DS];
    #pragma unroll
    for (int n = 0; n < DS; ++n) A[n] = -__expf(A_log[d * DS + n]);

    size_t hbase = ((size_t)(b * NC + c) * DS) * DI + d;
    #pragma unroll
    for (int n = 0; n < DS; ++n) h[n] = Hin[hbase + (size_t)n * DI];

    const float wdt = W_dt[d], bdt = b_dt[d], dpar = Dp[d];

    const int l0 = c * TCH;
    for (int l = l0; l < l0 + TCH; ++l) {
        const float* pr = proj + (size_t)(b * LSEQ + l) * 36;
        float dt = softplus_f(pr[32] * wdt + bdt);
        size_t xi = ((size_t)(b * LSEQ + l)) * DI + d;
        float x = xact[xi];
        float xdt = x * dt;
        float y = 0.f;
        #pragma unroll
        for (int n = 0; n < DS; ++n) {
            float dA = __expf(dt * A[n]);
            h[n] = dA * h[n] + xdt * pr[n];
            y += h[n] * pr[16 + n];
        }
        y += x * dpar;
        float z = xz[((size_t)(b * LSEQ + l)) * (2 * DI) + DI + d];
        float sz = z / (1.f + __expf(-z));
        ybf[xi] = f2bf(y * sz);
    }
}

// ---------------------------------------------------------------------------
extern "C" void kernel_launch(void* const* d_in, const int* in_sizes, int n_in,
                              void* d_out, int out_size, void* d_ws, size_t ws_size,
                              hipStream_t stream) {
    const float* x      = (const float*)d_in[0];
    const float* W_in   = (const float*)d_in[1];
    const float* conv_w = (const float*)d_in[2];
    const float* conv_b = (const float*)d_in[3];
    const float* W_x    = (const float*)d_in[4];
    const float* A_log  = (const float*)d_in[5];
    const float* Dp     = (const float*)d_in[6];
    const float* W_dt   = (const float*)d_in[7];
    const float* b_dt   = (const float*)d_in[8];
    const float* W_out  = (const float*)d_in[9];
    float* out = (float*)d_out;

    char* ws = (char*)d_ws;
    // workspace layout (bytes) -- total 126.5 MiB (proven in R1)
    float* XZ   = (float*)(ws + 0);            // B*L*4096*4 = 64 MiB
    float* XACT = (float*)(ws + 67108864);     // B*L*2048*4 = 32 MiB
    // overlay (dead before conv_silu writes XACT):
    unsigned short* Xb    = (unsigned short*)(ws + 67108864);   // 8 MiB
    unsigned short* W_inb = (unsigned short*)(ws + 75497472);   // 8 MiB
    float* PROJ = (float*)(ws + 100663296);    // ~0.56 MiB
    float* Pbuf = (float*)(ws + 101253120);    // 8 MiB
    float* Hbuf = (float*)(ws + 109641728);    // 8 MiB
    float* Hin  = (float*)(ws + 118030336);    // 8 MiB
    // overlay (dead after scan_phase2/3):
    unsigned short* Yb     = (unsigned short*)(ws + 101253120); // 16 MiB over Pbuf+Hbuf
    unsigned short* W_outb = (unsigned short*)(ws + 118030336); // 4 MiB over Hin

    const int M = BATCH * LSEQ;   // 4096

    // 0) converts for GEMM1 operands
    cvt_bf16<<<(M * DMODEL / 8 + 255) / 256, 256, 0, stream>>>(x, Xb, M * DMODEL / 8);
    cvt_bf16<<<(2 * DI * DMODEL / 8 + 255) / 256, 256, 0, stream>>>(W_in, W_inb, 2 * DI * DMODEL / 8);

    // 1) xz = x @ W_in.T  (M x 4096, K=1024) -- bf16 MFMA
    gemm_bf16_nt<<<dim3(2 * DI / 128, M / 128), 256, 0, stream>>>(
        Xb, W_inb, XZ, M, 2 * DI, DMODEL);

    // 2) depthwise conv + bias + SiLU -> XACT (fp32)
    conv_silu<<<(BATCH * LSEQ * DI) / 256, 256, 0, stream>>>(XZ, conv_w, conv_b, XACT);

    // 3) proj = XACT @ W_x.T  (padded row stride 36)
    gemm_proj<<<M, 64, 0, stream>>>(XACT, W_x, PROJ);

    // 4-6) chunked selective scan; phase3 emits y in bf16
    scan_phase1<<<dim3(DI / 256, NC, BATCH), 256, 0, stream>>>(
        XACT, PROJ, A_log, W_dt, b_dt, Pbuf, Hbuf);
    scan_phase2<<<(BATCH * DS * DI) / 256, 256, 0, stream>>>(Pbuf, Hbuf, Hin);
    scan_phase3<<<dim3(DI / 256, NC, BATCH), 256, 0, stream>>>(
        XACT, XZ, PROJ, A_log, W_dt, b_dt, Dp, Hin, Yb);

    // 7) convert W_out, then out = y @ W_out.T  (M x 1024, K=2048) -- bf16 MFMA
    cvt_bf16<<<(DMODEL * DI / 8 + 255) / 256, 256, 0, stream>>>(W_out, W_outb, DMODEL * DI / 8);
    gemm_bf16_nt<<<dim3(DMODEL / 128, M / 128), 256, 0, stream>>>(
        Yb, W_outb, out, M, DMODEL, DI);
}

// Round 3
// 346.281 us; speedup vs baseline: 2.9835x; 1.3647x over previous
//
#include <hip/hip_runtime.h>
#include <hip/hip_bf16.h>
#include <cstddef>

#define DMODEL 1024
#define DI     2048
#define DS     16
#define LSEQ   2048
#define BATCH  2
#define NC     32            // number of scan chunks
#define TCH    (LSEQ / NC)   // 64 steps per chunk

typedef __attribute__((ext_vector_type(8))) short short8;
typedef __attribute__((ext_vector_type(4))) float f32x4;
typedef __attribute__((ext_vector_type(8))) unsigned short us8;

__device__ __forceinline__ unsigned short f2bf(float f) {
    unsigned int u = __float_as_uint(f);
    unsigned int r = (u + 0x7fff + ((u >> 16) & 1)) >> 16;   // RNE
    return (unsigned short)r;
}

__device__ __forceinline__ void gload_lds16(const void* g, void* l) {
    __builtin_amdgcn_global_load_lds(
        (const __attribute__((address_space(1))) unsigned int*)g,
        (__attribute__((address_space(3))) unsigned int*)l, 16, 0, 0);
}

// ---------------------------------------------------------------------------
// f32 -> bf16 convert (vectorized, 8 elems/thread)
// ---------------------------------------------------------------------------
__global__ void cvt_bf16(const float* __restrict__ in, unsigned short* __restrict__ out, int n8) {
    int i = blockIdx.x * 256 + threadIdx.x;
    if (i >= n8) return;
    const float4* p = reinterpret_cast<const float4*>(in) + i * 2;
    float4 v0 = p[0], v1 = p[1];
    us8 o;
    o[0] = f2bf(v0.x); o[1] = f2bf(v0.y); o[2] = f2bf(v0.z); o[3] = f2bf(v0.w);
    o[4] = f2bf(v1.x); o[5] = f2bf(v1.y); o[6] = f2bf(v1.z); o[7] = f2bf(v1.w);
    *reinterpret_cast<us8*>(out + (size_t)i * 8) = o;
}

// W_x (33x2048 f32) -> bf16 padded to 48 rows (rows 33..47 = 0)
__global__ void prep_wx(const float* __restrict__ wx, unsigned short* __restrict__ out) {
    int i = blockIdx.x * 256 + threadIdx.x;      // 8 elems each, 48*2048/8 = 12288
    if (i >= 48 * 2048 / 8) return;
    size_t o = (size_t)i * 8;
    int row = (int)(o >> 11);
    us8 v;
    if (row < 33) {
        const float4* p = reinterpret_cast<const float4*>(wx + o);
        float4 v0 = p[0], v1 = p[1];
        v[0] = f2bf(v0.x); v[1] = f2bf(v0.y); v[2] = f2bf(v0.z); v[3] = f2bf(v0.w);
        v[4] = f2bf(v1.x); v[5] = f2bf(v1.y); v[6] = f2bf(v1.z); v[7] = f2bf(v1.w);
    } else {
        v = (us8)0;
    }
    *reinterpret_cast<us8*>(out + o) = v;
}

// ---------------------------------------------------------------------------
// bf16 MFMA GEMM (m97 structure): C[m,n] = sum_k A[m,k]*B[n,k], fp32 out.
// 128x128 tile, BK=32, 256 threads (4 waves, 2x2), 16x16x32 MFMA.
// ---------------------------------------------------------------------------
__global__ __launch_bounds__(256)
void gemm_bf16_nt(const unsigned short* __restrict__ A, const unsigned short* __restrict__ B,
                  float* __restrict__ C, int M, int N, int K) {
    __shared__ unsigned short As[128 * 32];
    __shared__ unsigned short Bs[128 * 32];

    const int tid = threadIdx.x;
    const int wv = tid >> 6, ln = tid & 63;
    const int m0 = blockIdx.y * 128, n0 = blockIdx.x * 128;
    const int wm = wv >> 1, wn = wv & 1;          // wave -> 64x64 quadrant

    f32x4 acc[4][4] = {};

    const int srow = ln >> 2;            // 0..15 within staging chunk
    const int scol = (ln & 3) * 8;       // k-element offset
    const int fr = ln & 15, fk = (ln >> 4) * 8;   // fragment row / k-offset

    for (int k0 = 0; k0 < K; k0 += 32) {
        #pragma unroll
        for (int c = 0; c < 2; ++c) {
            int ch = wv * 2 + c;                       // 0..7 : 16-row chunk
            const unsigned short* ga = A + (size_t)(m0 + ch * 16 + srow) * K + k0 + scol;
            gload_lds16(ga, &As[ch * 512]);
            const unsigned short* gb = B + (size_t)(n0 + ch * 16 + srow) * K + k0 + scol;
            gload_lds16(gb, &Bs[ch * 512]);
        }
        __syncthreads();

        short8 af[4], bf_[4];
        #pragma unroll
        for (int i = 0; i < 4; ++i) {
            af[i]  = *reinterpret_cast<const short8*>(&As[(wm * 64 + i * 16 + fr) * 32 + fk]);
            bf_[i] = *reinterpret_cast<const short8*>(&Bs[(wn * 64 + i * 16 + fr) * 32 + fk]);
        }
        #pragma unroll
        for (int i = 0; i < 4; ++i)
            #pragma unroll
            for (int j = 0; j < 4; ++j)
                acc[i][j] = __builtin_amdgcn_mfma_f32_16x16x32_bf16(af[i], bf_[j], acc[i][j], 0, 0, 0);
        __syncthreads();
    }

    const int cr = (ln >> 4) * 4, cc = ln & 15;
    #pragma unroll
    for (int i = 0; i < 4; ++i) {
        int row = m0 + wm * 64 + i * 16 + cr;
        #pragma unroll
        for (int j = 0; j < 4; ++j) {
            int col = n0 + wn * 64 + j * 16 + cc;
            #pragma unroll
            for (int r = 0; r < 4; ++r)
                C[(size_t)(row + r) * N + col] = acc[i][j][r];
        }
    }
}

// ---------------------------------------------------------------------------
// depthwise causal conv (width 4) + bias + SiLU; writes f32 (scan) + bf16 (proj)
// ---------------------------------------------------------------------------
__global__ void conv_silu(const float* __restrict__ xz, const float* __restrict__ cw,
                          const float* __restrict__ cb, float* __restrict__ xact,
                          unsigned short* __restrict__ xactb) {
    int idx = blockIdx.x * 256 + threadIdx.x;   // flat over B*L*DI
    if (idx >= BATCH * LSEQ * DI) return;
    int d = idx % DI;
    int l = (idx / DI) % LSEQ;
    int b = idx / (DI * LSEQ);

    float acc = cb[d];
    #pragma unroll
    for (int j = 0; j < 4; ++j) {
        int ls = l - 3 + j;
        if (ls >= 0)
            acc += xz[((size_t)(b * LSEQ + ls)) * (2 * DI) + d] * cw[d * 4 + j];
    }
    float v = acc / (1.f + __expf(-acc));
    xact[idx] = v;
    xactb[idx] = f2bf(v);
}

// ---------------------------------------------------------------------------
// skinny MFMA GEMM for proj: M=4096, N=48 (pad of 33), K=2048, K-split x4.
// Block: 256 thr (4 waves). Tile 64 rows x 48 cols; wave w owns rows w*16..+15.
// Partials written into the dead x_ssm half of XZ: projp[row*4096 + kz*36 + col]
// ---------------------------------------------------------------------------
__global__ __launch_bounds__(256)
void gemm_proj_mfma(const unsigned short* __restrict__ Xb, const unsigned short* __restrict__ Wxb,
                    float* __restrict__ projp) {
    __shared__ unsigned short As[64 * 32];   // 64 rows x 32 k
    __shared__ unsigned short Bs[48 * 32];   // 48 rows x 32 k

    const int tid = threadIdx.x;
    const int wv = tid >> 6, ln = tid & 63;
    const int m0 = blockIdx.x * 64;
    const int kz = blockIdx.y;
    const int srow = tid >> 2, skoff = (tid & 3) * 8;
    const int fr = ln & 15, fk = (ln >> 4) * 8;

    f32x4 acc[3] = {};

    const int k0base = kz * 512;
    for (int k0 = k0base; k0 < k0base + 512; k0 += 32) {
        gload_lds16(Xb + (size_t)(m0 + srow) * DI + k0 + skoff, &As[wv * 512]);
        if (wv < 3)
            gload_lds16(Wxb + (size_t)srow * DI + k0 + skoff, &Bs[wv * 512]);
        __syncthreads();

        short8 af = *reinterpret_cast<const short8*>(&As[(wv * 16 + fr) * 32 + fk]);
        #pragma unroll
        for (int j = 0; j < 3; ++j) {
            short8 bf_ = *reinterpret_cast<const short8*>(&Bs[(j * 16 + fr) * 32 + fk]);
            acc[j] = __builtin_amdgcn_mfma_f32_16x16x32_bf16(af, bf_, acc[j], 0, 0, 0);
        }
        __syncthreads();
    }

    const int cr = (ln >> 4) * 4, cc = ln & 15;
    #pragma unroll
    for (int j = 0; j < 3; ++j) {
        int col = j * 16 + cc;
        if (col < 33) {
            #pragma unroll
            for (int r = 0; r < 4; ++r) {
                int row = m0 + wv * 16 + cr + r;
                projp[(size_t)row * (2 * DI) + kz * 36 + col] = acc[j][r];
            }
        }
    }
}

// combine 4 K-split partials -> proj[row*36+col]
__global__ void proj_combine(const float* __restrict__ projp, float* __restrict__ proj) {
    int idx = blockIdx.x * 256 + threadIdx.x;
    if (idx >= BATCH * LSEQ * 33) return;
    int row = idx / 33, col = idx % 33;
    float s = 0.f;
    #pragma unroll
    for (int kz = 0; kz < 4; ++kz)
        s += projp[(size_t)row * (2 * DI) + kz * 36 + col];
    proj[(size_t)row * 36 + col] = s;
}

__device__ __forceinline__ float softplus_f(float v) {
    return (v > 20.f) ? v : log1pf(__expf(v));
}

// ---------------------------------------------------------------------------
// scan phase 1: per chunk per channel, P = prod(dA), Hend = local scan end
// ---------------------------------------------------------------------------
__global__ void scan_phase1(const float* __restrict__ xact, const float* __restrict__ proj,
                            const float* __restrict__ A_log, const float* __restrict__ W_dt,
                            const float* __restrict__ b_dt,
                            float* __restrict__ Pout, float* __restrict__ Hout) {
    const int d = blockIdx.x * 256 + threadIdx.x;
    const int c = blockIdx.y;
    const int b = blockIdx.z;

    float A[DS], h[DS], P[DS];
    #pragma unroll
    for (int n = 0; n < DS; ++n) {
        A[n] = -__expf(A_log[d * DS + n]);
        h[n] = 0.f;
        P[n] = 1.f;
    }
    const float wdt = W_dt[d], bdt = b_dt[d];

    const int l0 = c * TCH;
    for (int l = l0; l < l0 + TCH; ++l) {
        const float* pr = proj + (size_t)(b * LSEQ + l) * 36;
        float dt = softplus_f(pr[32] * wdt + bdt);
        float x = xact[((size_t)(b * LSEQ + l)) * DI + d];
        float xdt = x * dt;
        #pragma unroll
        for (int n = 0; n < DS; ++n) {
            float dA = __expf(dt * A[n]);
            h[n] = dA * h[n] + xdt * pr[n];
            P[n] *= dA;
        }
    }
    size_t base = ((size_t)(b * NC + c) * DS) * DI + d;
    #pragma unroll
    for (int n = 0; n < DS; ++n) {
        Pout[base + (size_t)n * DI] = P[n];
        Hout[base + (size_t)n * DI] = h[n];
    }
}

// ---------------------------------------------------------------------------
// scan phase 2: sequential combine over chunks
// ---------------------------------------------------------------------------
__global__ void scan_phase2(const float* __restrict__ P, const float* __restrict__ H,
                            float* __restrict__ Hin) {
    int idx = blockIdx.x * 256 + threadIdx.x;   // b*DS*DI + n*DI + d
    int b = idx / (DS * DI);
    int nd = idx % (DS * DI);
    float h = 0.f;
    for (int c = 0; c < NC; ++c) {
        size_t off = ((size_t)(b * NC + c) * DS * DI) + nd;
        Hin[off] = h;
        h = P[off] * h + H[off];
    }
}

// ---------------------------------------------------------------------------
// scan phase 3: full per-chunk scan with correct incoming state; fuse
// y = (scan_y + x*D) * silu(z); writes y as bf16 for the output GEMM
// ---------------------------------------------------------------------------
__global__ void scan_phase3(const float* __restrict__ xact, const float* __restrict__ xz,
                            const float* __restrict__ proj, const float* __restrict__ A_log,
                            const float* __restrict__ W_dt, const float* __restrict__ b_dt,
                            const float* __restrict__ Dp, const float* __restrict__ Hin,
                            unsigned short* __restrict__ ybf) {
    const int d = blockIdx.x * 256 + threadIdx.x;
    const int c = blockIdx.y;
    const int b = blockIdx.z;

    float A[DS], h[DS];
    #pragma unroll
    for (int n = 0; n < DS; ++n) A[n] = -__expf(A_log[d * DS + n]);

    size_t hbase = ((size_t)(b * NC + c) * DS) * DI + d;
    #pragma unroll
    for (int n = 0; n < DS; ++n) h[n] = Hin[hbase + (size_t)n * DI];

    const float wdt = W_dt[d], bdt = b_dt[d], dpar = Dp[d];

    const int l0 = c * TCH;
    for (int l = l0; l < l0 + TCH; ++l) {
        const float* pr = proj + (size_t)(b * LSEQ + l) * 36;
        float dt = softplus_f(pr[32] * wdt + bdt);
        size_t xi = ((size_t)(b * LSEQ + l)) * DI + d;
        float x = xact[xi];
        float xdt = x * dt;
        float y = 0.f;
        #pragma unroll
        for (int n = 0; n < DS; ++n) {
            float dA = __expf(dt * A[n]);
            h[n] = dA * h[n] + xdt * pr[n];
            y += h[n] * pr[16 + n];
        }
        y += x * dpar;
        float z = xz[((size_t)(b * LSEQ + l)) * (2 * DI) + DI + d];
        float sz = z / (1.f + __expf(-z));
        ybf[xi] = f2bf(y * sz);
    }
}

// ---------------------------------------------------------------------------
extern "C" void kernel_launch(void* const* d_in, const int* in_sizes, int n_in,
                              void* d_out, int out_size, void* d_ws, size_t ws_size,
                              hipStream_t stream) {
    const float* x      = (const float*)d_in[0];
    const float* W_in   = (const float*)d_in[1];
    const float* conv_w = (const float*)d_in[2];
    const float* conv_b = (const float*)d_in[3];
    const float* W_x    = (const float*)d_in[4];
    const float* A_log  = (const float*)d_in[5];
    const float* Dp     = (const float*)d_in[6];
    const float* W_dt   = (const float*)d_in[7];
    const float* b_dt   = (const float*)d_in[8];
    const float* W_out  = (const float*)d_in[9];
    float* out = (float*)d_out;

    char* ws = (char*)d_ws;
    // workspace layout (bytes) -- total 126,418,944 (same cap as R1/R2)
    float* XZ   = (float*)(ws + 0);            // B*L*4096*4 = 64 MiB; x-half doubles as projp scratch after conv
    float* XACT = (float*)(ws + 67108864);     // B*L*2048*4 = 32 MiB (f32, for scan)
    // overlay (dead before conv_silu writes XACT):
    unsigned short* Xb    = (unsigned short*)(ws + 67108864);   // 8 MiB
    unsigned short* W_inb = (unsigned short*)(ws + 75497472);   // 8 MiB
    float* PROJ = (float*)(ws + 100663296);    // 4096*36*4 = 0.5625 MiB
    float* Pbuf = (float*)(ws + 101253120);    // 8 MiB
    float* Hbuf = (float*)(ws + 109641728);    // 8 MiB
    float* Hin  = (float*)(ws + 118030336);    // 8 MiB
    // overlays:
    unsigned short* XACTB  = (unsigned short*)(ws + 101253120); // 16 MiB over Pbuf+Hbuf (live t2..t3)
    unsigned short* Yb     = (unsigned short*)(ws + 101253120); // 16 MiB over Pbuf+Hbuf (live t6..t7)
    unsigned short* Wxb48  = (unsigned short*)(ws + 122224640); // 192 KiB over Hin 2nd half (live t0..t3)
    unsigned short* W_outb = (unsigned short*)(ws + 118030336); // 4 MiB over Hin 1st half (live t7..)

    const int M = BATCH * LSEQ;   // 4096

    // 0) converts / prep
    cvt_bf16<<<(M * DMODEL / 8 + 255) / 256, 256, 0, stream>>>(x, Xb, M * DMODEL / 8);
    cvt_bf16<<<(2 * DI * DMODEL / 8 + 255) / 256, 256, 0, stream>>>(W_in, W_inb, 2 * DI * DMODEL / 8);
    prep_wx<<<(48 * 2048 / 8 + 255) / 256, 256, 0, stream>>>(W_x, Wxb48);

    // 1) xz = x @ W_in.T  (M x 4096, K=1024) -- bf16 MFMA
    gemm_bf16_nt<<<dim3(2 * DI / 128, M / 128), 256, 0, stream>>>(
        Xb, W_inb, XZ, M, 2 * DI, DMODEL);

    // 2) depthwise conv + bias + SiLU -> XACT (f32) + XACTB (bf16)
    conv_silu<<<(BATCH * LSEQ * DI) / 256, 256, 0, stream>>>(XZ, conv_w, conv_b, XACT, XACTB);

    // 3) proj = XACT @ W_x.T  -- skinny bf16 MFMA, K-split x4, partials into XZ x-half
    gemm_proj_mfma<<<dim3(M / 64, 4), 256, 0, stream>>>(XACTB, Wxb48, XZ);
    proj_combine<<<(M * 33 + 255) / 256, 256, 0, stream>>>(XZ, PROJ);

    // 4-6) chunked selective scan; phase3 emits y in bf16
    scan_phase1<<<dim3(DI / 256, NC, BATCH), 256, 0, stream>>>(
        XACT, PROJ, A_log, W_dt, b_dt, Pbuf, Hbuf);
    scan_phase2<<<(BATCH * DS * DI) / 256, 256, 0, stream>>>(Pbuf, Hbuf, Hin);
    scan_phase3<<<dim3(DI / 256, NC, BATCH), 256, 0, stream>>>(
        XACT, XZ, PROJ, A_log, W_dt, b_dt, Dp, Hin, Yb);

    // 7) convert W_out, then out = y @ W_out.T  (M x 1024, K=2048) -- bf16 MFMA
    cvt_bf16<<<(DMODEL * DI / 8 + 255) / 256, 256, 0, stream>>>(W_out, W_outb, DMODEL * DI / 8);
    gemm_bf16_nt<<<dim3(DMODEL / 128, M / 128), 256, 0, stream>>>(
        Yb, W_outb, out, M, DMODEL, DI);
}

// Round 4
// 278.598 us; speedup vs baseline: 3.7084x; 1.2429x over previous
//
#include <hip/hip_runtime.h>
#include <hip/hip_bf16.h>
#include <cstddef>

#define DMODEL 1024
#define DI     2048
#define DS     16
#define LSEQ   2048
#define BATCH  2
#define NC     64            // number of scan chunks
#define TCH    (LSEQ / NC)   // 32 steps per chunk

typedef __attribute__((ext_vector_type(8))) short short8;
typedef __attribute__((ext_vector_type(4))) float f32x4;
typedef __attribute__((ext_vector_type(8))) unsigned short us8;

__device__ __forceinline__ unsigned short f2bf(float f) {
    unsigned int u = __float_as_uint(f);
    unsigned int r = (u + 0x7fff + ((u >> 16) & 1)) >> 16;   // RNE
    return (unsigned short)r;
}
__device__ __forceinline__ float bf2f(unsigned short b) {
    return __uint_as_float(((unsigned int)b) << 16);
}

__device__ __forceinline__ void gload_lds16(const void* g, void* l) {
    __builtin_amdgcn_global_load_lds(
        (const __attribute__((address_space(1))) unsigned int*)g,
        (__attribute__((address_space(3))) unsigned int*)l, 16, 0, 0);
}

// ---------------------------------------------------------------------------
// f32 -> bf16 convert (vectorized, 8 elems/thread)
// ---------------------------------------------------------------------------
__global__ void cvt_bf16(const float* __restrict__ in, unsigned short* __restrict__ out, int n8) {
    int i = blockIdx.x * 256 + threadIdx.x;
    if (i >= n8) return;
    const float4* p = reinterpret_cast<const float4*>(in) + i * 2;
    float4 v0 = p[0], v1 = p[1];
    us8 o;
    o[0] = f2bf(v0.x); o[1] = f2bf(v0.y); o[2] = f2bf(v0.z); o[3] = f2bf(v0.w);
    o[4] = f2bf(v1.x); o[5] = f2bf(v1.y); o[6] = f2bf(v1.z); o[7] = f2bf(v1.w);
    *reinterpret_cast<us8*>(out + (size_t)i * 8) = o;
}

// W_x (33x2048 f32) -> bf16 padded to 48 rows (rows 33..47 = 0)
__global__ void prep_wx(const float* __restrict__ wx, unsigned short* __restrict__ out) {
    int i = blockIdx.x * 256 + threadIdx.x;
    if (i >= 48 * 2048 / 8) return;
    size_t o = (size_t)i * 8;
    int row = (int)(o >> 11);
    us8 v;
    if (row < 33) {
        const float4* p = reinterpret_cast<const float4*>(wx + o);
        float4 v0 = p[0], v1 = p[1];
        v[0] = f2bf(v0.x); v[1] = f2bf(v0.y); v[2] = f2bf(v0.z); v[3] = f2bf(v0.w);
        v[4] = f2bf(v1.x); v[5] = f2bf(v1.y); v[6] = f2bf(v1.z); v[7] = f2bf(v1.w);
    } else {
        v = (us8)0;
    }
    *reinterpret_cast<us8*>(out + o) = v;
}

// A table, transposed: At[n][d] = -exp(A_log[d][n])
__global__ void prep_A(const float* __restrict__ A_log, float* __restrict__ At) {
    int i = blockIdx.x * 256 + threadIdx.x;   // i = n*DI + d
    if (i >= DS * DI) return;
    int n = i / DI, d = i % DI;
    At[i] = -__expf(A_log[d * DS + n]);
}

// ---------------------------------------------------------------------------
// bf16 MFMA GEMM (m97 structure) with leading dims: C[m,n]=sum_k A[m,k]*B[n,k]
// ---------------------------------------------------------------------------
__global__ __launch_bounds__(256)
void gemm_bf16_nt(const unsigned short* __restrict__ A, int lda,
                  const unsigned short* __restrict__ B, int ldb,
                  float* __restrict__ C, int M, int N, int K) {
    __shared__ unsigned short As[128 * 32];
    __shared__ unsigned short Bs[128 * 32];

    const int tid = threadIdx.x;
    const int wv = tid >> 6, ln = tid & 63;
    const int m0 = blockIdx.y * 128, n0 = blockIdx.x * 128;
    const int wm = wv >> 1, wn = wv & 1;

    f32x4 acc[4][4] = {};

    const int srow = ln >> 2;
    const int scol = (ln & 3) * 8;
    const int fr = ln & 15, fk = (ln >> 4) * 8;

    for (int k0 = 0; k0 < K; k0 += 32) {
        #pragma unroll
        for (int c = 0; c < 2; ++c) {
            int ch = wv * 2 + c;
            gload_lds16(A + (size_t)(m0 + ch * 16 + srow) * lda + k0 + scol, &As[ch * 512]);
            gload_lds16(B + (size_t)(n0 + ch * 16 + srow) * ldb + k0 + scol, &Bs[ch * 512]);
        }
        __syncthreads();

        short8 af[4], bf_[4];
        #pragma unroll
        for (int i = 0; i < 4; ++i) {
            af[i]  = *reinterpret_cast<const short8*>(&As[(wm * 64 + i * 16 + fr) * 32 + fk]);
            bf_[i] = *reinterpret_cast<const short8*>(&Bs[(wn * 64 + i * 16 + fr) * 32 + fk]);
        }
        #pragma unroll
        for (int i = 0; i < 4; ++i)
            #pragma unroll
            for (int j = 0; j < 4; ++j)
                acc[i][j] = __builtin_amdgcn_mfma_f32_16x16x32_bf16(af[i], bf_[j], acc[i][j], 0, 0, 0);
        __syncthreads();
    }

    const int cr = (ln >> 4) * 4, cc = ln & 15;
    #pragma unroll
    for (int i = 0; i < 4; ++i) {
        int row = m0 + wm * 64 + i * 16 + cr;
        #pragma unroll
        for (int j = 0; j < 4; ++j) {
            int col = n0 + wn * 64 + j * 16 + cc;
            #pragma unroll
            for (int r = 0; r < 4; ++r)
                C[(size_t)(row + r) * N + col] = acc[i][j][r];
        }
    }
}

// ---------------------------------------------------------------------------
// depthwise causal conv (width 4) + bias + SiLU -> bf16 only, 8 d's per thread
// ---------------------------------------------------------------------------
__global__ void conv_silu(const float* __restrict__ xz, const float* __restrict__ cw,
                          const float* __restrict__ cb, unsigned short* __restrict__ xactb) {
    int i = blockIdx.x * 256 + threadIdx.x;        // over B*L*DI/8
    if (i >= BATCH * LSEQ * DI / 8) return;
    int d0 = (i % (DI / 8)) * 8;
    int l  = (i / (DI / 8)) % LSEQ;
    int b  = i / ((DI / 8) * LSEQ);

    float4 w[8];
    #pragma unroll
    for (int j = 0; j < 8; ++j)
        w[j] = *reinterpret_cast<const float4*>(cw + (d0 + j) * 4);

    float acc[8];
    #pragma unroll
    for (int j = 0; j < 8; ++j) acc[j] = cb[d0 + j];

    #pragma unroll
    for (int t = 0; t < 4; ++t) {
        int ls = l - 3 + t;
        if (ls >= 0) {
            const float* src = xz + (size_t)(b * LSEQ + ls) * (2 * DI) + d0;
            float4 a0 = *reinterpret_cast<const float4*>(src);
            float4 a1 = *reinterpret_cast<const float4*>(src + 4);
            float sv[8] = {a0.x, a0.y, a0.z, a0.w, a1.x, a1.y, a1.z, a1.w};
            #pragma unroll
            for (int j = 0; j < 8; ++j) {
                float wt = (t == 0) ? w[j].x : (t == 1) ? w[j].y : (t == 2) ? w[j].z : w[j].w;
                acc[j] += sv[j] * wt;
            }
        }
    }
    us8 o;
    #pragma unroll
    for (int j = 0; j < 8; ++j) {
        float v = acc[j] / (1.f + __expf(-acc[j]));
        o[j] = f2bf(v);
    }
    *reinterpret_cast<us8*>(xactb + (size_t)i * 8) = o;
}

// ---------------------------------------------------------------------------
// skinny MFMA GEMM for proj: partials into dead x-cols of XZ
// ---------------------------------------------------------------------------
__global__ __launch_bounds__(256)
void gemm_proj_mfma(const unsigned short* __restrict__ Xb, const unsigned short* __restrict__ Wxb,
                    float* __restrict__ projp) {
    __shared__ unsigned short As[64 * 32];
    __shared__ unsigned short Bs[48 * 32];

    const int tid = threadIdx.x;
    const int wv = tid >> 6, ln = tid & 63;
    const int m0 = blockIdx.x * 64;
    const int kz = blockIdx.y;
    const int srow = tid >> 2, skoff = (tid & 3) * 8;
    const int fr = ln & 15, fk = (ln >> 4) * 8;

    f32x4 acc[3] = {};

    const int k0base = kz * 512;
    for (int k0 = k0base; k0 < k0base + 512; k0 += 32) {
        gload_lds16(Xb + (size_t)(m0 + srow) * DI + k0 + skoff, &As[wv * 512]);
        if (wv < 3)
            gload_lds16(Wxb + (size_t)srow * DI + k0 + skoff, &Bs[wv * 512]);
        __syncthreads();

        short8 af = *reinterpret_cast<const short8*>(&As[(wv * 16 + fr) * 32 + fk]);
        #pragma unroll
        for (int j = 0; j < 3; ++j) {
            short8 bf_ = *reinterpret_cast<const short8*>(&Bs[(j * 16 + fr) * 32 + fk]);
            acc[j] = __builtin_amdgcn_mfma_f32_16x16x32_bf16(af, bf_, acc[j], 0, 0, 0);
        }
        __syncthreads();
    }

    const int cr = (ln >> 4) * 4, cc = ln & 15;
    #pragma unroll
    for (int j = 0; j < 3; ++j) {
        int col = j * 16 + cc;
        if (col < 33) {
            #pragma unroll
            for (int r = 0; r < 4; ++r) {
                int row = m0 + wv * 16 + cr + r;
                projp[(size_t)row * (2 * DI) + kz * 36 + col] = acc[j][r];
            }
        }
    }
}

// combine 4 K-split partials -> PROJ[row*36+col]
__global__ void proj_combine(const float* __restrict__ projp, float* __restrict__ proj) {
    int idx = blockIdx.x * 256 + threadIdx.x;
    if (idx >= BATCH * LSEQ * 33) return;
    int row = idx / 33, col = idx % 33;
    float s = 0.f;
    #pragma unroll
    for (int kz = 0; kz < 4; ++kz)
        s += projp[(size_t)row * (2 * DI) + kz * 36 + col];
    proj[(size_t)row * 36 + col] = s;
}

__device__ __forceinline__ float softplus_f(float v) {
    return (v > 20.f) ? v : log1pf(__expf(v));
}

// ---------------------------------------------------------------------------
// scan phase 1: local scan (h0=0). Emits y_local (bf16), S prefix (bf16 into
// XZ dead x-cols 1024..2047), chunk-end Hend (f32) and dtsum (f32).
// ---------------------------------------------------------------------------
__global__ __launch_bounds__(256)
void scan_phase1(const unsigned short* __restrict__ xactb, const float* __restrict__ proj,
                 const float* __restrict__ At, const float* __restrict__ W_dt,
                 const float* __restrict__ b_dt, float* __restrict__ Hend,
                 float* __restrict__ dtsum, unsigned short* __restrict__ yloc,
                 float* __restrict__ XZf) {
    const int d = blockIdx.x * 256 + threadIdx.x;
    const int c = blockIdx.y;
    const int b = blockIdx.z;

    float A[DS], h[DS];
    #pragma unroll
    for (int n = 0; n < DS; ++n) { A[n] = At[n * DI + d]; h[n] = 0.f; }
    const float wdt = W_dt[d], bdt = b_dt[d];
    float ssum = 0.f;

    const int l0 = c * TCH;
    for (int l = l0; l < l0 + TCH; ++l) {
        const size_t row = (size_t)(b * LSEQ + l);
        const float* pr = proj + row * 36;
        float dt = softplus_f(pr[32] * wdt + bdt);
        ssum += dt;
        ((unsigned short*)(XZf + row * (2 * DI)))[2048 + d] = f2bf(ssum);
        float x = bf2f(xactb[row * DI + d]);
        float xdt = x * dt;
        float y = 0.f;
        #pragma unroll
        for (int n = 0; n < DS; ++n) {
            float e = __expf(dt * A[n]);
            h[n] = e * h[n] + xdt * pr[n];
            y += h[n] * pr[16 + n];
        }
        yloc[row * DI + d] = f2bf(y);
    }
    size_t base = ((size_t)(b * NC + c) * DS) * DI + d;
    #pragma unroll
    for (int n = 0; n < DS; ++n) Hend[base + (size_t)n * DI] = h[n];
    dtsum[(size_t)(b * NC + c) * DI + d] = ssum;
}

// ---------------------------------------------------------------------------
// scan phase 2: in-place chunk combine; Hend -> Hin (state before chunk)
// P(chunk) = exp(A * dtsum)
// ---------------------------------------------------------------------------
__global__ void scan_phase2(float* __restrict__ H, const float* __restrict__ dtsum,
                            const float* __restrict__ At) {
    int idx = blockIdx.x * 256 + threadIdx.x;   // b*DS*DI + n*DI + d
    int b = idx / (DS * DI);
    int r = idx % (DS * DI);
    int n = r / DI, d = r % DI;
    float A = At[n * DI + d];
    float h = 0.f;
    for (int c = 0; c < NC; ++c) {
        size_t off = ((size_t)(b * NC + c) * DS + n) * DI + d;
        float He = H[off];
        float P = __expf(A * dtsum[(size_t)(b * NC + c) * DI + d]);
        H[off] = h;                 // now Hin
        h = P * h + He;
    }
}

// ---------------------------------------------------------------------------
// scan phase 3: fully parallel correction + gate.
// y = y_local + sum_n C_n * exp(A_n*S) * Hin_n + x*D;  out = y * silu(z)
// Writes bf16 y into XZ dead x-cols 0..1023 (bf16 slots 0..2047).
// ---------------------------------------------------------------------------
__global__ __launch_bounds__(256)
void scan_phase3(const unsigned short* __restrict__ xactb, const unsigned short* __restrict__ yloc,
                 const float* __restrict__ proj, const float* __restrict__ At,
                 const float* __restrict__ Dp, const float* __restrict__ Hin,
                 float* __restrict__ XZf) {
    __shared__ float HinS[DS][256];
    __shared__ float AS_[DS][256];

    const int tid = threadIdx.x;
    const int dt0 = blockIdx.x;        // 0..7
    const int c = blockIdx.y;          // 0..NC-1
    const int b = blockIdx.z;
    const int d = dt0 * 256 + tid;

    #pragma unroll
    for (int n = 0; n < DS; ++n) {
        HinS[n][tid] = Hin[((size_t)(b * NC + c) * DS + n) * DI + d];
        AS_[n][tid]  = At[n * DI + d];
    }
    __syncthreads();

    const float Dv = Dp[d];
    const int l0 = c * TCH;
    for (int l = l0; l < l0 + TCH; ++l) {
        const size_t row = (size_t)(b * LSEQ + l);
        const float* pr = proj + row * 36;
        float* xzrow = XZf + row * (2 * DI);
        float S = bf2f(((const unsigned short*)xzrow)[2048 + d]);
        float yl = bf2f(yloc[row * DI + d]);
        float x  = bf2f(xactb[row * DI + d]);
        float z  = xzrow[2048 + d];
        float corr = 0.f;
        #pragma unroll
        for (int n = 0; n < DS; ++n)
            corr += pr[16 + n] * __expf(AS_[n][tid] * S) * HinS[n][tid];
        float y = yl + corr + x * Dv;
        float sz = z / (1.f + __expf(-z));
        ((unsigned short*)xzrow)[d] = f2bf(y * sz);
    }
}

// ---------------------------------------------------------------------------
extern "C" void kernel_launch(void* const* d_in, const int* in_sizes, int n_in,
                              void* d_out, int out_size, void* d_ws, size_t ws_size,
                              hipStream_t stream) {
    const float* x      = (const float*)d_in[0];
    const float* W_in   = (const float*)d_in[1];
    const float* conv_w = (const float*)d_in[2];
    const float* conv_b = (const float*)d_in[3];
    const float* W_x    = (const float*)d_in[4];
    const float* A_log  = (const float*)d_in[5];
    const float* Dp     = (const float*)d_in[6];
    const float* W_dt   = (const float*)d_in[7];
    const float* b_dt   = (const float*)d_in[8];
    const float* W_out  = (const float*)d_in[9];
    float* out = (float*)d_out;

    char* ws = (char*)d_ws;
    // workspace layout (bytes), total ~123.4 MiB:
    float* XZ = (float*)(ws + 0);                               // 64 MiB [t1..t7: xz, projp, S, Yb]
    unsigned short* XACTB = (unsigned short*)(ws + 67108864);   // 16 MiB [t2..t6]
    unsigned short* Xb    = (unsigned short*)(ws + 67108864);   // 8 MiB  [t0..t1, dead at t2]
    unsigned short* W_inb = (unsigned short*)(ws + 75497472);   // 8 MiB  [t0..t1]
    float* Hbuf  = (float*)(ws + 83886080);                     // 16 MiB [t4..t6] (Hend->Hin)
    unsigned short* Wxb48 = (unsigned short*)(ws + 83886080);   // 192 KiB [t0..t3, dead at t4]
    unsigned short* YLOC  = (unsigned short*)(ws + 100663296);  // 16 MiB [t4..t6]
    float* PROJ  = (float*)(ws + 117440512);                    // 0.56 MiB [t3..t6]
    float* DTSUM = (float*)(ws + 118030336);                    // 1 MiB [t4..t5]
    float* Abuf  = (float*)(ws + 119078912);                    // 128 KiB [t0..t6]
    unsigned short* W_outb = (unsigned short*)(ws + 119209984); // 4 MiB [t6.5..t7]

    const int M = BATCH * LSEQ;   // 4096

    // t0) converts / prep
    cvt_bf16<<<M * DMODEL / 8 / 256, 256, 0, stream>>>(x, Xb, M * DMODEL / 8);
    cvt_bf16<<<2 * DI * DMODEL / 8 / 256, 256, 0, stream>>>(W_in, W_inb, 2 * DI * DMODEL / 8);
    prep_wx<<<48, 256, 0, stream>>>(W_x, Wxb48);
    prep_A<<<DS * DI / 256, 256, 0, stream>>>(A_log, Abuf);

    // t1) xz = x @ W_in.T
    gemm_bf16_nt<<<dim3(2 * DI / 128, M / 128), 256, 0, stream>>>(
        Xb, DMODEL, W_inb, DMODEL, XZ, M, 2 * DI, DMODEL);

    // t2) depthwise conv + SiLU -> XACTB (bf16)
    conv_silu<<<BATCH * LSEQ * DI / 8 / 256, 256, 0, stream>>>(XZ, conv_w, conv_b, XACTB);

    // t3) proj
    gemm_proj_mfma<<<dim3(M / 64, 4), 256, 0, stream>>>(XACTB, Wxb48, XZ);
    proj_combine<<<(M * 33 + 255) / 256, 256, 0, stream>>>(XZ, PROJ);

    // t4-t6) chunked scan
    scan_phase1<<<dim3(DI / 256, NC, BATCH), 256, 0, stream>>>(
        XACTB, PROJ, Abuf, W_dt, b_dt, Hbuf, DTSUM, YLOC, XZ);
    scan_phase2<<<BATCH * DS * DI / 256, 256, 0, stream>>>(Hbuf, DTSUM, Abuf);
    scan_phase3<<<dim3(DI / 256, NC, BATCH), 256, 0, stream>>>(
        XACTB, YLOC, PROJ, Abuf, Dp, Hbuf, XZ);

    // t7) out = y @ W_out.T   (A = Yb strided inside XZ, lda = 8192 bf16)
    cvt_bf16<<<DMODEL * DI / 8 / 256, 256, 0, stream>>>(W_out, W_outb, DMODEL * DI / 8);
    gemm_bf16_nt<<<dim3(DMODEL / 128, M / 128), 256, 0, stream>>>(
        (const unsigned short*)XZ, 2 * DI * 2, W_outb, DI, out, M, DMODEL, DI);
}

// Round 5
// 246.105 us; speedup vs baseline: 4.1980x; 1.1320x over previous
//
#include <hip/hip_runtime.h>
#include <hip/hip_bf16.h>
#include <cstddef>

#define DMODEL 1024
#define DI     2048
#define DS     16
#define LSEQ   2048
#define BATCH  2
#define NC     128           // number of scan chunks
#define TCH    (LSEQ / NC)   // 16 steps per chunk

typedef __attribute__((ext_vector_type(8))) short short8;
typedef __attribute__((ext_vector_type(4))) float f32x4;
typedef __attribute__((ext_vector_type(2))) float f32x2;
typedef __attribute__((ext_vector_type(8))) unsigned short us8;

__device__ __forceinline__ unsigned short f2bf(float f) {
    unsigned int u = __float_as_uint(f);
    unsigned int r = (u + 0x7fff + ((u >> 16) & 1)) >> 16;   // RNE
    return (unsigned short)r;
}
__device__ __forceinline__ float bf2f(unsigned short b) {
    return __uint_as_float(((unsigned int)b) << 16);
}

__device__ __forceinline__ float fexp2(float x) {
#if __has_builtin(__builtin_amdgcn_exp2f)
    return __builtin_amdgcn_exp2f(x);
#else
    return exp2f(x);
#endif
}
__device__ __forceinline__ float flog2(float x) {
#if __has_builtin(__builtin_amdgcn_logf)
    return __builtin_amdgcn_logf(x);
#else
    return log2f(x);
#endif
}

#define LOG2E 1.4426950408889634f
#define RLOG2E 0.6931471805599453f

__device__ __forceinline__ float softplus_f(float v) {
    return (v > 20.f) ? v : flog2(1.f + fexp2(v * LOG2E)) * RLOG2E;
}

__device__ __forceinline__ void gload_lds16(const void* g, void* l) {
    __builtin_amdgcn_global_load_lds(
        (const __attribute__((address_space(1))) unsigned int*)g,
        (__attribute__((address_space(3))) unsigned int*)l, 16, 0, 0);
}

// ---------------------------------------------------------------------------
// f32 -> bf16 convert (vectorized, 8 elems/thread)
// ---------------------------------------------------------------------------
__global__ void cvt_bf16(const float* __restrict__ in, unsigned short* __restrict__ out, int n8) {
    int i = blockIdx.x * 256 + threadIdx.x;
    if (i >= n8) return;
    const float4* p = reinterpret_cast<const float4*>(in) + i * 2;
    float4 v0 = p[0], v1 = p[1];
    us8 o;
    o[0] = f2bf(v0.x); o[1] = f2bf(v0.y); o[2] = f2bf(v0.z); o[3] = f2bf(v0.w);
    o[4] = f2bf(v1.x); o[5] = f2bf(v1.y); o[6] = f2bf(v1.z); o[7] = f2bf(v1.w);
    *reinterpret_cast<us8*>(out + (size_t)i * 8) = o;
}

// W_x (33x2048 f32) -> bf16 padded to 48 rows (rows 33..47 = 0)
__global__ void prep_wx(const float* __restrict__ wx, unsigned short* __restrict__ out) {
    int i = blockIdx.x * 256 + threadIdx.x;
    if (i >= 48 * 2048 / 8) return;
    size_t o = (size_t)i * 8;
    int row = (int)(o >> 11);
    us8 v;
    if (row < 33) {
        const float4* p = reinterpret_cast<const float4*>(wx + o);
        float4 v0 = p[0], v1 = p[1];
        v[0] = f2bf(v0.x); v[1] = f2bf(v0.y); v[2] = f2bf(v0.z); v[3] = f2bf(v0.w);
        v[4] = f2bf(v1.x); v[5] = f2bf(v1.y); v[6] = f2bf(v1.z); v[7] = f2bf(v1.w);
    } else {
        v = (us8)0;
    }
    *reinterpret_cast<us8*>(out + o) = v;
}

// A table, transposed + log2e-folded: At2[n][d] = -exp(A_log[d][n]) * log2(e)
__global__ void prep_A(const float* __restrict__ A_log, float* __restrict__ At2) {
    int i = blockIdx.x * 256 + threadIdx.x;   // i = n*DI + d
    if (i >= DS * DI) return;
    int n = i / DI, d = i % DI;
    At2[i] = -__expf(A_log[d * DS + n]) * LOG2E;
}

// ---------------------------------------------------------------------------
// bf16 MFMA GEMM (m97 structure) with leading dims: C[m,n]=sum_k A[m,k]*B[n,k]
// ---------------------------------------------------------------------------
__global__ __launch_bounds__(256)
void gemm_bf16_nt(const unsigned short* __restrict__ A, int lda,
                  const unsigned short* __restrict__ B, int ldb,
                  float* __restrict__ C, int M, int N, int K) {
    __shared__ unsigned short As[128 * 32];
    __shared__ unsigned short Bs[128 * 32];

    const int tid = threadIdx.x;
    const int wv = tid >> 6, ln = tid & 63;
    const int m0 = blockIdx.y * 128, n0 = blockIdx.x * 128;
    const int wm = wv >> 1, wn = wv & 1;

    f32x4 acc[4][4] = {};

    const int srow = ln >> 2;
    const int scol = (ln & 3) * 8;
    const int fr = ln & 15, fk = (ln >> 4) * 8;

    for (int k0 = 0; k0 < K; k0 += 32) {
        #pragma unroll
        for (int c = 0; c < 2; ++c) {
            int ch = wv * 2 + c;
            gload_lds16(A + (size_t)(m0 + ch * 16 + srow) * lda + k0 + scol, &As[ch * 512]);
            gload_lds16(B + (size_t)(n0 + ch * 16 + srow) * ldb + k0 + scol, &Bs[ch * 512]);
        }
        __syncthreads();

        short8 af[4], bf_[4];
        #pragma unroll
        for (int i = 0; i < 4; ++i) {
            af[i]  = *reinterpret_cast<const short8*>(&As[(wm * 64 + i * 16 + fr) * 32 + fk]);
            bf_[i] = *reinterpret_cast<const short8*>(&Bs[(wn * 64 + i * 16 + fr) * 32 + fk]);
        }
        #pragma unroll
        for (int i = 0; i < 4; ++i)
            #pragma unroll
            for (int j = 0; j < 4; ++j)
                acc[i][j] = __builtin_amdgcn_mfma_f32_16x16x32_bf16(af[i], bf_[j], acc[i][j], 0, 0, 0);
        __syncthreads();
    }

    const int cr = (ln >> 4) * 4, cc = ln & 15;
    #pragma unroll
    for (int i = 0; i < 4; ++i) {
        int row = m0 + wm * 64 + i * 16 + cr;
        #pragma unroll
        for (int j = 0; j < 4; ++j) {
            int col = n0 + wn * 64 + j * 16 + cc;
            #pragma unroll
            for (int r = 0; r < 4; ++r)
                C[(size_t)(row + r) * N + col] = acc[i][j][r];
        }
    }
}

// ---------------------------------------------------------------------------
// depthwise causal conv (width 4) + bias + SiLU -> bf16 only, 8 d's per thread
// ---------------------------------------------------------------------------
__global__ void conv_silu(const float* __restrict__ xz, const float* __restrict__ cw,
                          const float* __restrict__ cb, unsigned short* __restrict__ xactb) {
    int i = blockIdx.x * 256 + threadIdx.x;        // over B*L*DI/8
    if (i >= BATCH * LSEQ * DI / 8) return;
    int d0 = (i % (DI / 8)) * 8;
    int l  = (i / (DI / 8)) % LSEQ;
    int b  = i / ((DI / 8) * LSEQ);

    float4 w[8];
    #pragma unroll
    for (int j = 0; j < 8; ++j)
        w[j] = *reinterpret_cast<const float4*>(cw + (d0 + j) * 4);

    float acc[8];
    #pragma unroll
    for (int j = 0; j < 8; ++j) acc[j] = cb[d0 + j];

    #pragma unroll
    for (int t = 0; t < 4; ++t) {
        int ls = l - 3 + t;
        if (ls >= 0) {
            const float* src = xz + (size_t)(b * LSEQ + ls) * (2 * DI) + d0;
            float4 a0 = *reinterpret_cast<const float4*>(src);
            float4 a1 = *reinterpret_cast<const float4*>(src + 4);
            float sv[8] = {a0.x, a0.y, a0.z, a0.w, a1.x, a1.y, a1.z, a1.w};
            #pragma unroll
            for (int j = 0; j < 8; ++j) {
                float wt = (t == 0) ? w[j].x : (t == 1) ? w[j].y : (t == 2) ? w[j].z : w[j].w;
                acc[j] += sv[j] * wt;
            }
        }
    }
    us8 o;
    #pragma unroll
    for (int j = 0; j < 8; ++j) {
        float v = acc[j] / (1.f + __expf(-acc[j]));
        o[j] = f2bf(v);
    }
    *reinterpret_cast<us8*>(xactb + (size_t)i * 8) = o;
}

// ---------------------------------------------------------------------------
// skinny MFMA GEMM for proj: partials into dead x-cols of XZ
// ---------------------------------------------------------------------------
__global__ __launch_bounds__(256)
void gemm_proj_mfma(const unsigned short* __restrict__ Xb, const unsigned short* __restrict__ Wxb,
                    float* __restrict__ projp) {
    __shared__ unsigned short As[64 * 32];
    __shared__ unsigned short Bs[48 * 32];

    const int tid = threadIdx.x;
    const int wv = tid >> 6, ln = tid & 63;
    const int m0 = blockIdx.x * 64;
    const int kz = blockIdx.y;
    const int srow = tid >> 2, skoff = (tid & 3) * 8;
    const int fr = ln & 15, fk = (ln >> 4) * 8;

    f32x4 acc[3] = {};

    const int k0base = kz * 512;
    for (int k0 = k0base; k0 < k0base + 512; k0 += 32) {
        gload_lds16(Xb + (size_t)(m0 + srow) * DI + k0 + skoff, &As[wv * 512]);
        if (wv < 3)
            gload_lds16(Wxb + (size_t)srow * DI + k0 + skoff, &Bs[wv * 512]);
        __syncthreads();

        short8 af = *reinterpret_cast<const short8*>(&As[(wv * 16 + fr) * 32 + fk]);
        #pragma unroll
        for (int j = 0; j < 3; ++j) {
            short8 bf_ = *reinterpret_cast<const short8*>(&Bs[(j * 16 + fr) * 32 + fk]);
            acc[j] = __builtin_amdgcn_mfma_f32_16x16x32_bf16(af, bf_, acc[j], 0, 0, 0);
        }
        __syncthreads();
    }

    const int cr = (ln >> 4) * 4, cc = ln & 15;
    #pragma unroll
    for (int j = 0; j < 3; ++j) {
        int col = j * 16 + cc;
        if (col < 33) {
            #pragma unroll
            for (int r = 0; r < 4; ++r) {
                int row = m0 + wv * 16 + cr + r;
                projp[(size_t)row * (2 * DI) + kz * 36 + col] = acc[j][r];
            }
        }
    }
}

// combine 4 K-split partials -> PROJ[row*36+col]
__global__ void proj_combine(const float* __restrict__ projp, float* __restrict__ proj) {
    int idx = blockIdx.x * 256 + threadIdx.x;
    if (idx >= BATCH * LSEQ * 33) return;
    int row = idx / 33, col = idx % 33;
    float s = 0.f;
    #pragma unroll
    for (int kz = 0; kz < 4; ++kz)
        s += projp[(size_t)row * (2 * DI) + kz * 36 + col];
    proj[(size_t)row * 36 + col] = s;
}

// ---------------------------------------------------------------------------
// scan phase 1: local scan (h0=0), packed f32x2 math, exp2-folded A.
// Emits y_local (bf16), S prefix (bf16 into XZ x-cols 1024..2047),
// chunk-end Hend (bf16) and dtsum (f32).
// ---------------------------------------------------------------------------
__global__ __launch_bounds__(256)
void scan_phase1(const unsigned short* __restrict__ xactb, const float* __restrict__ proj,
                 const float* __restrict__ At2, const float* __restrict__ W_dt,
                 const float* __restrict__ b_dt, unsigned short* __restrict__ Hend,
                 float* __restrict__ dtsum, unsigned short* __restrict__ yloc,
                 float* __restrict__ XZf) {
    const int d = blockIdx.x * 256 + threadIdx.x;
    const int c = blockIdx.y;
    const int b = blockIdx.z;

    f32x2 A2[DS / 2], h2[DS / 2];
    #pragma unroll
    for (int p = 0; p < DS / 2; ++p) {
        A2[p] = (f32x2){At2[(2 * p) * DI + d], At2[(2 * p + 1) * DI + d]};
        h2[p] = (f32x2){0.f, 0.f};
    }
    const float wdt = W_dt[d], bdt = b_dt[d];
    float ssum = 0.f;

    const int l0 = c * TCH;
    #pragma unroll 2
    for (int l = l0; l < l0 + TCH; ++l) {
        const size_t row = (size_t)(b * LSEQ + l);
        const float* pr = proj + row * 36;          // block-uniform -> s_load
        float dt = softplus_f(pr[32] * wdt + bdt);
        ssum += dt;
        ((unsigned short*)(XZf + row * (2 * DI)))[2048 + d] = f2bf(ssum);
        float x = bf2f(xactb[row * DI + d]);
        float xdt = x * dt;
        f32x2 xdt2 = (f32x2){xdt, xdt};
        f32x2 y2 = (f32x2){0.f, 0.f};
        #pragma unroll
        for (int p = 0; p < DS / 2; ++p) {
            f32x2 t = A2[p] * dt;
            f32x2 e2 = (f32x2){fexp2(t.x), fexp2(t.y)};
            h2[p] = e2 * h2[p] + xdt2 * (f32x2){pr[2 * p], pr[2 * p + 1]};
            y2 += h2[p] * (f32x2){pr[16 + 2 * p], pr[17 + 2 * p]};
        }
        yloc[row * DI + d] = f2bf(y2.x + y2.y);
    }
    size_t base = ((size_t)(b * NC + c) * DS) * DI + d;
    #pragma unroll
    for (int p = 0; p < DS / 2; ++p) {
        Hend[base + (size_t)(2 * p) * DI]     = f2bf(h2[p].x);
        Hend[base + (size_t)(2 * p + 1) * DI] = f2bf(h2[p].y);
    }
    dtsum[(size_t)(b * NC + c) * DI + d] = ssum;
}

// ---------------------------------------------------------------------------
// scan phase 2: in-place chunk combine (bf16 H); Hend -> Hin
// ---------------------------------------------------------------------------
__global__ void scan_phase2(unsigned short* __restrict__ H, const float* __restrict__ dtsum,
                            const float* __restrict__ At2) {
    int idx = blockIdx.x * 256 + threadIdx.x;   // b*DS*DI + n*DI + d
    int b = idx / (DS * DI);
    int r = idx % (DS * DI);
    int n = r / DI, d = r % DI;
    float A2 = At2[n * DI + d];
    float h = 0.f;
    #pragma unroll 4
    for (int c = 0; c < NC; ++c) {
        size_t off = ((size_t)(b * NC + c) * DS + n) * DI + d;
        float He = bf2f(H[off]);
        float P = fexp2(A2 * dtsum[(size_t)(b * NC + c) * DI + d]);
        H[off] = f2bf(h);                 // now Hin
        h = P * h + He;
    }
}

// ---------------------------------------------------------------------------
// scan phase 3: fully parallel correction + gate, all-register state.
// y = y_local + sum_n C_n * exp(A_n*S) * Hin_n + x*D;  out = y * silu(z)
// ---------------------------------------------------------------------------
__global__ __launch_bounds__(256)
void scan_phase3(const unsigned short* __restrict__ xactb, const unsigned short* __restrict__ yloc,
                 const float* __restrict__ proj, const float* __restrict__ At2,
                 const float* __restrict__ Dp, const unsigned short* __restrict__ Hin,
                 float* __restrict__ XZf) {
    const int tid = threadIdx.x;
    const int d = blockIdx.x * 256 + tid;
    const int c = blockIdx.y;
    const int b = blockIdx.z;

    f32x2 A2[DS / 2], Hn2[DS / 2];
    size_t hbase = ((size_t)(b * NC + c) * DS) * DI + d;
    #pragma unroll
    for (int p = 0; p < DS / 2; ++p) {
        A2[p]  = (f32x2){At2[(2 * p) * DI + d], At2[(2 * p + 1) * DI + d]};
        Hn2[p] = (f32x2){bf2f(Hin[hbase + (size_t)(2 * p) * DI]),
                         bf2f(Hin[hbase + (size_t)(2 * p + 1) * DI])};
    }

    const float Dv = Dp[d];
    const int l0 = c * TCH;
    #pragma unroll 2
    for (int l = l0; l < l0 + TCH; ++l) {
        const size_t row = (size_t)(b * LSEQ + l);
        const float* pr = proj + row * 36;          // block-uniform -> s_load
        float* xzrow = XZf + row * (2 * DI);
        float S  = bf2f(((const unsigned short*)xzrow)[2048 + d]);
        float yl = bf2f(yloc[row * DI + d]);
        float x  = bf2f(xactb[row * DI + d]);
        float z  = xzrow[2048 + d];
        f32x2 corr2 = (f32x2){0.f, 0.f};
        #pragma unroll
        for (int p = 0; p < DS / 2; ++p) {
            f32x2 t = A2[p] * S;
            f32x2 e2 = (f32x2){fexp2(t.x), fexp2(t.y)};
            corr2 += (f32x2){pr[16 + 2 * p], pr[17 + 2 * p]} * e2 * Hn2[p];
        }
        float y = yl + corr2.x + corr2.y + x * Dv;
        float sz = z / (1.f + __expf(-z));
        ((unsigned short*)xzrow)[d] = f2bf(y * sz);
    }
}

// ---------------------------------------------------------------------------
extern "C" void kernel_launch(void* const* d_in, const int* in_sizes, int n_in,
                              void* d_out, int out_size, void* d_ws, size_t ws_size,
                              hipStream_t stream) {
    const float* x      = (const float*)d_in[0];
    const float* W_in   = (const float*)d_in[1];
    const float* conv_w = (const float*)d_in[2];
    const float* conv_b = (const float*)d_in[3];
    const float* W_x    = (const float*)d_in[4];
    const float* A_log  = (const float*)d_in[5];
    const float* Dp     = (const float*)d_in[6];
    const float* W_dt   = (const float*)d_in[7];
    const float* b_dt   = (const float*)d_in[8];
    const float* W_out  = (const float*)d_in[9];
    float* out = (float*)d_out;

    char* ws = (char*)d_ws;
    // workspace layout (bytes), total ~118.7 MiB:
    float* XZ = (float*)(ws + 0);                               // 64 MiB [t1..t7]
    unsigned short* XACTB = (unsigned short*)(ws + 67108864);   // 16 MiB [t2..t6]
    unsigned short* Xb    = (unsigned short*)(ws + 67108864);   // 8 MiB  [t0..t1, dead at t2]
    unsigned short* W_inb = (unsigned short*)(ws + 75497472);   // 8 MiB  [t0..t1]
    unsigned short* Hbuf  = (unsigned short*)(ws + 83886080);   // 16 MiB [t4..t6] (Hend->Hin, bf16)
    unsigned short* Wxb48 = (unsigned short*)(ws + 83886080);   // 192 KiB [t0..t3, dead at t4]
    unsigned short* YLOC  = (unsigned short*)(ws + 100663296);  // 16 MiB [t4..t6]
    float* PROJ  = (float*)(ws + 117440512);                    // 0.56 MiB [t3..t6]
    float* DTSUM = (float*)(ws + 118030336);                    // 2 MiB [t4..t5]
    float* Abuf  = (float*)(ws + 120127488);                    // 128 KiB [t0..t6]
    unsigned short* W_outb = (unsigned short*)(ws + 120258560); // 4 MiB [t6.5..t7]

    const int M = BATCH * LSEQ;   // 4096

    // t0) converts / prep
    cvt_bf16<<<M * DMODEL / 8 / 256, 256, 0, stream>>>(x, Xb, M * DMODEL / 8);
    cvt_bf16<<<2 * DI * DMODEL / 8 / 256, 256, 0, stream>>>(W_in, W_inb, 2 * DI * DMODEL / 8);
    prep_wx<<<48, 256, 0, stream>>>(W_x, Wxb48);
    prep_A<<<DS * DI / 256, 256, 0, stream>>>(A_log, Abuf);

    // t1) xz = x @ W_in.T
    gemm_bf16_nt<<<dim3(2 * DI / 128, M / 128), 256, 0, stream>>>(
        Xb, DMODEL, W_inb, DMODEL, XZ, M, 2 * DI, DMODEL);

    // t2) depthwise conv + SiLU -> XACTB (bf16)
    conv_silu<<<BATCH * LSEQ * DI / 8 / 256, 256, 0, stream>>>(XZ, conv_w, conv_b, XACTB);

    // t3) proj
    gemm_proj_mfma<<<dim3(M / 64, 4), 256, 0, stream>>>(XACTB, Wxb48, XZ);
    proj_combine<<<(M * 33 + 255) / 256, 256, 0, stream>>>(XZ, PROJ);

    // t4-t6) chunked scan
    scan_phase1<<<dim3(DI / 256, NC, BATCH), 256, 0, stream>>>(
        XACTB, PROJ, Abuf, W_dt, b_dt, Hbuf, DTSUM, YLOC, XZ);
    scan_phase2<<<BATCH * DS * DI / 256, 256, 0, stream>>>(Hbuf, DTSUM, Abuf);
    scan_phase3<<<dim3(DI / 256, NC, BATCH), 256, 0, stream>>>(
        XACTB, YLOC, PROJ, Abuf, Dp, Hbuf, XZ);

    // t7) out = y @ W_out.T   (A = Yb strided inside XZ, lda = 8192 bf16)
    cvt_bf16<<<DMODEL * DI / 8 / 256, 256, 0, stream>>>(W_out, W_outb, DMODEL * DI / 8);
    gemm_bf16_nt<<<dim3(DMODEL / 128, M / 128), 256, 0, stream>>>(
        (const unsigned short*)XZ, 2 * DI * 2, W_outb, DI, out, M, DMODEL, DI);
}

// Round 6
// 221.650 us; speedup vs baseline: 4.6611x; 1.1103x over previous
//
#include <hip/hip_runtime.h>
#include <hip/hip_bf16.h>
#include <cstddef>

#define DMODEL 1024
#define DI     2048
#define DS     16
#define LSEQ   2048
#define BATCH  2
#define NC     128           // number of scan chunks
#define TCH    (LSEQ / NC)   // 16 steps per chunk

typedef __attribute__((ext_vector_type(8))) short short8;
typedef __attribute__((ext_vector_type(4))) float f32x4;
typedef __attribute__((ext_vector_type(2))) float f32x2;
typedef __attribute__((ext_vector_type(8))) unsigned short us8;

__device__ __forceinline__ unsigned short f2bf(float f) {
    unsigned int u = __float_as_uint(f);
    unsigned int r = (u + 0x7fff + ((u >> 16) & 1)) >> 16;   // RNE
    return (unsigned short)r;
}
__device__ __forceinline__ float bf2f(unsigned short b) {
    return __uint_as_float(((unsigned int)b) << 16);
}

__device__ __forceinline__ float fexp2(float x) {
#if __has_builtin(__builtin_amdgcn_exp2f)
    return __builtin_amdgcn_exp2f(x);
#else
    return exp2f(x);
#endif
}
__device__ __forceinline__ float flog2(float x) {
#if __has_builtin(__builtin_amdgcn_logf)
    return __builtin_amdgcn_logf(x);
#else
    return log2f(x);
#endif
}

#define LOG2E 1.4426950408889634f
#define RLOG2E 0.6931471805599453f

__device__ __forceinline__ float softplus_f(float v) {
    return (v > 20.f) ? v : flog2(1.f + fexp2(v * LOG2E)) * RLOG2E;
}

__device__ __forceinline__ void gload_lds16(const void* g, void* l) {
    __builtin_amdgcn_global_load_lds(
        (const __attribute__((address_space(1))) unsigned int*)g,
        (__attribute__((address_space(3))) unsigned int*)l, 16, 0, 0);
}

// ---------------------------------------------------------------------------
// f32 -> bf16 convert
// ---------------------------------------------------------------------------
__global__ void cvt_bf16(const float* __restrict__ in, unsigned short* __restrict__ out, int n8) {
    int i = blockIdx.x * 256 + threadIdx.x;
    if (i >= n8) return;
    const float4* p = reinterpret_cast<const float4*>(in) + i * 2;
    float4 v0 = p[0], v1 = p[1];
    us8 o;
    o[0] = f2bf(v0.x); o[1] = f2bf(v0.y); o[2] = f2bf(v0.z); o[3] = f2bf(v0.w);
    o[4] = f2bf(v1.x); o[5] = f2bf(v1.y); o[6] = f2bf(v1.z); o[7] = f2bf(v1.w);
    *reinterpret_cast<us8*>(out + (size_t)i * 8) = o;
}

// W_x (33x2048 f32) -> bf16 padded to 48 rows
__global__ void prep_wx(const float* __restrict__ wx, unsigned short* __restrict__ out) {
    int i = blockIdx.x * 256 + threadIdx.x;
    if (i >= 48 * 2048 / 8) return;
    size_t o = (size_t)i * 8;
    int row = (int)(o >> 11);
    us8 v;
    if (row < 33) {
        const float4* p = reinterpret_cast<const float4*>(wx + o);
        float4 v0 = p[0], v1 = p[1];
        v[0] = f2bf(v0.x); v[1] = f2bf(v0.y); v[2] = f2bf(v0.z); v[3] = f2bf(v0.w);
        v[4] = f2bf(v1.x); v[5] = f2bf(v1.y); v[6] = f2bf(v1.z); v[7] = f2bf(v1.w);
    } else {
        v = (us8)0;
    }
    *reinterpret_cast<us8*>(out + o) = v;
}

// A table, transposed + log2e-folded
__global__ void prep_A(const float* __restrict__ A_log, float* __restrict__ At2) {
    int i = blockIdx.x * 256 + threadIdx.x;
    if (i >= DS * DI) return;
    int n = i / DI, d = i % DI;
    At2[i] = -__expf(A_log[d * DS + n]) * LOG2E;
}

// ---------------------------------------------------------------------------
// GEMM1: 256x256 tile, 8 waves, BK=32, 4-deep LDS pipeline, counted vmcnt,
// k-unit XOR swizzle (pre-swizzled global src + swizzled ds_read), bf16 out.
// C[m,n] = sum_k A[m,k]*B[n,k];  M=N=4096, K=1024 fixed.
// ---------------------------------------------------------------------------
#define NT1 32
__global__ __launch_bounds__(512, 2)
void gemm1_pipe(const unsigned short* __restrict__ A, const unsigned short* __restrict__ B,
                unsigned short* __restrict__ C) {
    __shared__ unsigned short lds[4][2][256 * 32];   // 128 KiB

    const int tid = threadIdx.x;
    const int wid = tid >> 6, ln = tid & 63;
    const int wm = wid >> 2, wn = wid & 3;           // 2 x 4 waves; wave owns 128x64

    int wg = blockIdx.x;
    wg = (wg & 7) * 32 + (wg >> 3);                  // XCD swizzle (256 % 8 == 0)
    const int m0 = (wg >> 4) * 256;
    const int n0 = (wg & 15) * 256;

    const int srow = tid >> 2;                       // 0..127 staging row
    const int sun  = tid & 3;                        // staging k-unit slot
    const int ksrc = ((sun ^ ((srow >> 1) & 3)) * 8);  // inverse-swizzled source k

    const int fr = ln & 15;
    const int fku = (ln >> 4);                       // frag k-unit 0..3

    f32x4 acc[8][4] = {};

    #define STAGE1(kt)                                                                     \
        do {                                                                               \
            const int bq_ = (kt) & 3;                                                      \
            gload_lds16(A + (size_t)(m0 + srow) * 1024 + (kt) * 32 + ksrc,                 \
                        &lds[bq_][0][srow * 32 + sun * 8]);                                \
            gload_lds16(A + (size_t)(m0 + 128 + srow) * 1024 + (kt) * 32 + ksrc,           \
                        &lds[bq_][0][(128 + srow) * 32 + sun * 8]);                        \
            gload_lds16(B + (size_t)(n0 + srow) * 1024 + (kt) * 32 + ksrc,                 \
                        &lds[bq_][1][srow * 32 + sun * 8]);                                \
            gload_lds16(B + (size_t)(n0 + 128 + srow) * 1024 + (kt) * 32 + ksrc,           \
                        &lds[bq_][1][(128 + srow) * 32 + sun * 8]);                        \
        } while (0)

    STAGE1(0); STAGE1(1); STAGE1(2);
    asm volatile("s_waitcnt vmcnt(8)" ::: "memory");   // K-tile 0 landed
    __builtin_amdgcn_s_barrier();
    __builtin_amdgcn_sched_barrier(0);

    for (int kt = 0; kt < NT1; ++kt) {
        const int bq = kt & 3;
        if (kt + 3 < NT1) STAGE1(kt + 3);            // targets buf[(kt-1)&3]: read-done

        short8 af_lo[4], bfr[4], af_hi[4];
        #pragma unroll
        for (int i = 0; i < 4; ++i) {
            int r = wm * 128 + i * 16 + fr;
            int u = fku ^ ((r >> 1) & 3);
            af_lo[i] = *reinterpret_cast<const short8*>(&lds[bq][0][r * 32 + u * 8]);
        }
        #pragma unroll
        for (int j = 0; j < 4; ++j) {
            int r = wn * 64 + j * 16 + fr;
            int u = fku ^ ((r >> 1) & 3);
            bfr[j] = *reinterpret_cast<const short8*>(&lds[bq][1][r * 32 + u * 8]);
        }
        #pragma unroll
        for (int i = 0; i < 4; ++i) {
            int r = wm * 128 + (4 + i) * 16 + fr;
            int u = fku ^ ((r >> 1) & 3);
            af_hi[i] = *reinterpret_cast<const short8*>(&lds[bq][0][r * 32 + u * 8]);
        }
        __builtin_amdgcn_sched_barrier(0);
        __builtin_amdgcn_s_setprio(1);
        #pragma unroll
        for (int i = 0; i < 4; ++i)
            #pragma unroll
            for (int j = 0; j < 4; ++j)
                acc[i][j] = __builtin_amdgcn_mfma_f32_16x16x32_bf16(af_lo[i], bfr[j], acc[i][j], 0, 0, 0);
        __builtin_amdgcn_s_setprio(0);
        __builtin_amdgcn_sched_barrier(0);
        __builtin_amdgcn_s_setprio(1);
        #pragma unroll
        for (int i = 0; i < 4; ++i)
            #pragma unroll
            for (int j = 0; j < 4; ++j)
                acc[4 + i][j] = __builtin_amdgcn_mfma_f32_16x16x32_bf16(af_hi[i], bfr[j], acc[4 + i][j], 0, 0, 0);
        __builtin_amdgcn_s_setprio(0);
        __builtin_amdgcn_sched_barrier(0);

        if (kt < NT1 - 3)       asm volatile("s_waitcnt vmcnt(8)" ::: "memory");
        else if (kt == NT1 - 3) asm volatile("s_waitcnt vmcnt(4)" ::: "memory");
        else if (kt == NT1 - 2) asm volatile("s_waitcnt vmcnt(0)" ::: "memory");
        __builtin_amdgcn_s_barrier();
        __builtin_amdgcn_sched_barrier(0);
    }
    #undef STAGE1

    const int cr = (ln >> 4) * 4, cc = ln & 15;
    #pragma unroll
    for (int i = 0; i < 8; ++i) {
        int row = m0 + wm * 128 + i * 16 + cr;
        #pragma unroll
        for (int j = 0; j < 4; ++j) {
            int col = n0 + wn * 64 + j * 16 + cc;
            #pragma unroll
            for (int r = 0; r < 4; ++r)
                C[(size_t)(row + r) * 4096 + col] = f2bf(acc[i][j][r]);
        }
    }
}

// ---------------------------------------------------------------------------
// m97-structure bf16 GEMM (f32 out) -- used for GEMM3
// ---------------------------------------------------------------------------
__global__ __launch_bounds__(256)
void gemm_bf16_nt(const unsigned short* __restrict__ A, int lda,
                  const unsigned short* __restrict__ B, int ldb,
                  float* __restrict__ C, int M, int N, int K) {
    __shared__ unsigned short As[128 * 32];
    __shared__ unsigned short Bs[128 * 32];

    const int tid = threadIdx.x;
    const int wv = tid >> 6, ln = tid & 63;
    const int m0 = blockIdx.y * 128, n0 = blockIdx.x * 128;
    const int wm = wv >> 1, wn = wv & 1;

    f32x4 acc[4][4] = {};

    const int srow = ln >> 2;
    const int scol = (ln & 3) * 8;
    const int fr = ln & 15, fk = (ln >> 4) * 8;

    for (int k0 = 0; k0 < K; k0 += 32) {
        #pragma unroll
        for (int c = 0; c < 2; ++c) {
            int ch = wv * 2 + c;
            gload_lds16(A + (size_t)(m0 + ch * 16 + srow) * lda + k0 + scol, &As[ch * 512]);
            gload_lds16(B + (size_t)(n0 + ch * 16 + srow) * ldb + k0 + scol, &Bs[ch * 512]);
        }
        __syncthreads();

        short8 af[4], bf_[4];
        #pragma unroll
        for (int i = 0; i < 4; ++i) {
            af[i]  = *reinterpret_cast<const short8*>(&As[(wm * 64 + i * 16 + fr) * 32 + fk]);
            bf_[i] = *reinterpret_cast<const short8*>(&Bs[(wn * 64 + i * 16 + fr) * 32 + fk]);
        }
        #pragma unroll
        for (int i = 0; i < 4; ++i)
            #pragma unroll
            for (int j = 0; j < 4; ++j)
                acc[i][j] = __builtin_amdgcn_mfma_f32_16x16x32_bf16(af[i], bf_[j], acc[i][j], 0, 0, 0);
        __syncthreads();
    }

    const int cr = (ln >> 4) * 4, cc = ln & 15;
    #pragma unroll
    for (int i = 0; i < 4; ++i) {
        int row = m0 + wm * 64 + i * 16 + cr;
        #pragma unroll
        for (int j = 0; j < 4; ++j) {
            int col = n0 + wn * 64 + j * 16 + cc;
            #pragma unroll
            for (int r = 0; r < 4; ++r)
                C[(size_t)(row + r) * N + col] = acc[i][j][r];
        }
    }
}

// ---------------------------------------------------------------------------
// depthwise causal conv (width 4) + bias + SiLU; bf16 in (XZb), bf16 out
// ---------------------------------------------------------------------------
__global__ void conv_silu(const unsigned short* __restrict__ xzb, const float* __restrict__ cw,
                          const float* __restrict__ cb, unsigned short* __restrict__ xactb) {
    int i = blockIdx.x * 256 + threadIdx.x;        // over B*L*DI/8
    if (i >= BATCH * LSEQ * DI / 8) return;
    int d0 = (i % (DI / 8)) * 8;
    int l  = (i / (DI / 8)) % LSEQ;
    int b  = i / ((DI / 8) * LSEQ);

    float4 w[8];
    #pragma unroll
    for (int j = 0; j < 8; ++j)
        w[j] = *reinterpret_cast<const float4*>(cw + (d0 + j) * 4);

    float acc[8];
    #pragma unroll
    for (int j = 0; j < 8; ++j) acc[j] = cb[d0 + j];

    #pragma unroll
    for (int t = 0; t < 4; ++t) {
        int ls = l - 3 + t;
        if (ls >= 0) {
            us8 v = *reinterpret_cast<const us8*>(xzb + (size_t)(b * LSEQ + ls) * 4096 + d0);
            #pragma unroll
            for (int j = 0; j < 8; ++j) {
                float wt = (t == 0) ? w[j].x : (t == 1) ? w[j].y : (t == 2) ? w[j].z : w[j].w;
                acc[j] += bf2f(v[j]) * wt;
            }
        }
    }
    us8 o;
    #pragma unroll
    for (int j = 0; j < 8; ++j) {
        float v = acc[j] / (1.f + __expf(-acc[j]));
        o[j] = f2bf(v);
    }
    *reinterpret_cast<us8*>(xactb + (size_t)i * 8) = o;
}

// ---------------------------------------------------------------------------
// skinny MFMA GEMM for proj: partials -> PROJP[row*144 + kz*36 + col]
// ---------------------------------------------------------------------------
__global__ __launch_bounds__(256)
void gemm_proj_mfma(const unsigned short* __restrict__ Xb, const unsigned short* __restrict__ Wxb,
                    float* __restrict__ projp) {
    __shared__ unsigned short As[64 * 32];
    __shared__ unsigned short Bs[48 * 32];

    const int tid = threadIdx.x;
    const int wv = tid >> 6, ln = tid & 63;
    const int m0 = blockIdx.x * 64;
    const int kz = blockIdx.y;
    const int srow = tid >> 2, skoff = (tid & 3) * 8;
    const int fr = ln & 15, fk = (ln >> 4) * 8;

    f32x4 acc[3] = {};

    const int k0base = kz * 512;
    for (int k0 = k0base; k0 < k0base + 512; k0 += 32) {
        gload_lds16(Xb + (size_t)(m0 + srow) * DI + k0 + skoff, &As[wv * 512]);
        if (wv < 3)
            gload_lds16(Wxb + (size_t)srow * DI + k0 + skoff, &Bs[wv * 512]);
        __syncthreads();

        short8 af = *reinterpret_cast<const short8*>(&As[(wv * 16 + fr) * 32 + fk]);
        #pragma unroll
        for (int j = 0; j < 3; ++j) {
            short8 bf_ = *reinterpret_cast<const short8*>(&Bs[(j * 16 + fr) * 32 + fk]);
            acc[j] = __builtin_amdgcn_mfma_f32_16x16x32_bf16(af, bf_, acc[j], 0, 0, 0);
        }
        __syncthreads();
    }

    const int cr = (ln >> 4) * 4, cc = ln & 15;
    #pragma unroll
    for (int j = 0; j < 3; ++j) {
        int col = j * 16 + cc;
        if (col < 33) {
            #pragma unroll
            for (int r = 0; r < 4; ++r) {
                int row = m0 + wv * 16 + cr + r;
                projp[(size_t)row * 144 + kz * 36 + col] = acc[j][r];
            }
        }
    }
}

// combine 4 K-split partials
__global__ void proj_combine(const float* __restrict__ projp, float* __restrict__ proj) {
    int idx = blockIdx.x * 256 + threadIdx.x;
    if (idx >= BATCH * LSEQ * 33) return;
    int row = idx / 33, col = idx % 33;
    float s = 0.f;
    #pragma unroll
    for (int kz = 0; kz < 4; ++kz)
        s += projp[(size_t)row * 144 + kz * 36 + col];
    proj[(size_t)row * 36 + col] = s;
}

// ---------------------------------------------------------------------------
// scan phase 1: local scan (h0=0); y_local (bf16), S prefix (bf16 into XZb
// x-cols), Hend (bf16), dtsum (f32)
// ---------------------------------------------------------------------------
__global__ __launch_bounds__(256)
void scan_phase1(const unsigned short* __restrict__ xactb, const float* __restrict__ proj,
                 const float* __restrict__ At2, const float* __restrict__ W_dt,
                 const float* __restrict__ b_dt, unsigned short* __restrict__ Hend,
                 float* __restrict__ dtsum, unsigned short* __restrict__ yloc,
                 unsigned short* __restrict__ XZb) {
    const int d = blockIdx.x * 256 + threadIdx.x;
    const int c = blockIdx.y;
    const int b = blockIdx.z;

    f32x2 A2[DS / 2], h2[DS / 2];
    #pragma unroll
    for (int p = 0; p < DS / 2; ++p) {
        A2[p] = (f32x2){At2[(2 * p) * DI + d], At2[(2 * p + 1) * DI + d]};
        h2[p] = (f32x2){0.f, 0.f};
    }
    const float wdt = W_dt[d], bdt = b_dt[d];
    float ssum = 0.f;

    const int l0 = c * TCH;
    #pragma unroll 2
    for (int l = l0; l < l0 + TCH; ++l) {
        const size_t row = (size_t)(b * LSEQ + l);
        const float* pr = proj + row * 36;
        float dt = softplus_f(pr[32] * wdt + bdt);
        ssum += dt;
        XZb[row * 4096 + d] = f2bf(ssum);
        float x = bf2f(xactb[row * DI + d]);
        float xdt = x * dt;
        f32x2 xdt2 = (f32x2){xdt, xdt};
        f32x2 y2 = (f32x2){0.f, 0.f};
        #pragma unroll
        for (int p = 0; p < DS / 2; ++p) {
            f32x2 t = A2[p] * dt;
            f32x2 e2 = (f32x2){fexp2(t.x), fexp2(t.y)};
            h2[p] = e2 * h2[p] + xdt2 * (f32x2){pr[2 * p], pr[2 * p + 1]};
            y2 += h2[p] * (f32x2){pr[16 + 2 * p], pr[17 + 2 * p]};
        }
        yloc[row * DI + d] = f2bf(y2.x + y2.y);
    }
    size_t base = ((size_t)(b * NC + c) * DS) * DI + d;
    #pragma unroll
    for (int p = 0; p < DS / 2; ++p) {
        Hend[base + (size_t)(2 * p) * DI]     = f2bf(h2[p].x);
        Hend[base + (size_t)(2 * p + 1) * DI] = f2bf(h2[p].y);
    }
    dtsum[(size_t)(b * NC + c) * DI + d] = ssum;
}

// ---------------------------------------------------------------------------
// scan phase 2: in-place chunk combine (bf16 H); Hend -> Hin
// ---------------------------------------------------------------------------
__global__ void scan_phase2(unsigned short* __restrict__ H, const float* __restrict__ dtsum,
                            const float* __restrict__ At2) {
    int idx = blockIdx.x * 256 + threadIdx.x;
    int b = idx / (DS * DI);
    int r = idx % (DS * DI);
    int n = r / DI, d = r % DI;
    float A2 = At2[n * DI + d];
    float h = 0.f;
    #pragma unroll 4
    for (int c = 0; c < NC; ++c) {
        size_t off = ((size_t)(b * NC + c) * DS + n) * DI + d;
        float He = bf2f(H[off]);
        float P = fexp2(A2 * dtsum[(size_t)(b * NC + c) * DI + d]);
        H[off] = f2bf(h);
        h = P * h + He;
    }
}

// ---------------------------------------------------------------------------
// scan phase 3: parallel correction + gate; y (bf16) over S slots in XZb
// ---------------------------------------------------------------------------
__global__ __launch_bounds__(256)
void scan_phase3(const unsigned short* __restrict__ xactb, const unsigned short* __restrict__ yloc,
                 const float* __restrict__ proj, const float* __restrict__ At2,
                 const float* __restrict__ Dp, const unsigned short* __restrict__ Hin,
                 unsigned short* __restrict__ XZb) {
    const int tid = threadIdx.x;
    const int d = blockIdx.x * 256 + tid;
    const int c = blockIdx.y;
    const int b = blockIdx.z;

    f32x2 A2[DS / 2], Hn2[DS / 2];
    size_t hbase = ((size_t)(b * NC + c) * DS) * DI + d;
    #pragma unroll
    for (int p = 0; p < DS / 2; ++p) {
        A2[p]  = (f32x2){At2[(2 * p) * DI + d], At2[(2 * p + 1) * DI + d]};
        Hn2[p] = (f32x2){bf2f(Hin[hbase + (size_t)(2 * p) * DI]),
                         bf2f(Hin[hbase + (size_t)(2 * p + 1) * DI])};
    }

    const float Dv = Dp[d];
    const int l0 = c * TCH;
    #pragma unroll 2
    for (int l = l0; l < l0 + TCH; ++l) {
        const size_t row = (size_t)(b * LSEQ + l);
        const float* pr = proj + row * 36;
        unsigned short* xzrow = XZb + row * 4096;
        float S  = bf2f(xzrow[d]);
        float yl = bf2f(yloc[row * DI + d]);
        float x  = bf2f(xactb[row * DI + d]);
        float z  = bf2f(xzrow[2048 + d]);
        f32x2 corr2 = (f32x2){0.f, 0.f};
        #pragma unroll
        for (int p = 0; p < DS / 2; ++p) {
            f32x2 t = A2[p] * S;
            f32x2 e2 = (f32x2){fexp2(t.x), fexp2(t.y)};
            corr2 += (f32x2){pr[16 + 2 * p], pr[17 + 2 * p]} * e2 * Hn2[p];
        }
        float y = yl + corr2.x + corr2.y + x * Dv;
        float sz = z / (1.f + __expf(-z));
        xzrow[d] = f2bf(y * sz);
    }
}

// ---------------------------------------------------------------------------
extern "C" void kernel_launch(void* const* d_in, const int* in_sizes, int n_in,
                              void* d_out, int out_size, void* d_ws, size_t ws_size,
                              hipStream_t stream) {
    const float* x      = (const float*)d_in[0];
    const float* W_in   = (const float*)d_in[1];
    const float* conv_w = (const float*)d_in[2];
    const float* conv_b = (const float*)d_in[3];
    const float* W_x    = (const float*)d_in[4];
    const float* A_log  = (const float*)d_in[5];
    const float* Dp     = (const float*)d_in[6];
    const float* W_dt   = (const float*)d_in[7];
    const float* b_dt   = (const float*)d_in[8];
    const float* W_out  = (const float*)d_in[9];
    float* out = (float*)d_out;

    char* ws = (char*)d_ws;
    // workspace layout (bytes), ~107 MiB, no overlays:
    unsigned short* XZb   = (unsigned short*)(ws + 0);           // 32 MiB  [t1..t7]
    unsigned short* XACTB = (unsigned short*)(ws + 33554432);    // 16 MiB  [t2..t6]
    unsigned short* Xb    = (unsigned short*)(ws + 50331648);    // 8 MiB   [t0..t1]
    unsigned short* W_inb = (unsigned short*)(ws + 58720256);    // 8 MiB   [t0..t1]
    unsigned short* Hbuf  = (unsigned short*)(ws + 67108864);    // 16 MiB  [t4..t6]
    unsigned short* YLOC  = (unsigned short*)(ws + 83886080);    // 16 MiB  [t4..t6]
    float* PROJ  = (float*)(ws + 100663296);                     // 0.56 MiB
    float* DTSUM = (float*)(ws + 101711872);                     // 2 MiB
    float* PROJP = (float*)(ws + 103809024);                     // 2.25 MiB
    float* Abuf  = (float*)(ws + 106954752);                     // 128 KiB
    unsigned short* W_outb = (unsigned short*)(ws + 108003328);  // 4 MiB
    unsigned short* Wxb48  = (unsigned short*)(ws + 112197632);  // 192 KiB

    const int M = BATCH * LSEQ;   // 4096

    // t0) converts / prep
    cvt_bf16<<<M * DMODEL / 8 / 256, 256, 0, stream>>>(x, Xb, M * DMODEL / 8);
    cvt_bf16<<<2 * DI * DMODEL / 8 / 256, 256, 0, stream>>>(W_in, W_inb, 2 * DI * DMODEL / 8);
    prep_wx<<<48, 256, 0, stream>>>(W_x, Wxb48);
    prep_A<<<DS * DI / 256, 256, 0, stream>>>(A_log, Abuf);

    // t1) xz = x @ W_in.T -> bf16 XZb (pipelined 256^2 kernel)
    gemm1_pipe<<<256, 512, 0, stream>>>(Xb, W_inb, XZb);

    // t2) depthwise conv + SiLU -> XACTB (bf16)
    conv_silu<<<BATCH * LSEQ * DI / 8 / 256, 256, 0, stream>>>(XZb, conv_w, conv_b, XACTB);

    // t3) proj
    gemm_proj_mfma<<<dim3(M / 64, 4), 256, 0, stream>>>(XACTB, Wxb48, PROJP);
    proj_combine<<<(M * 33 + 255) / 256, 256, 0, stream>>>(PROJP, PROJ);

    // t4-t6) chunked scan
    scan_phase1<<<dim3(DI / 256, NC, BATCH), 256, 0, stream>>>(
        XACTB, PROJ, Abuf, W_dt, b_dt, Hbuf, DTSUM, YLOC, XZb);
    scan_phase2<<<BATCH * DS * DI / 256, 256, 0, stream>>>(Hbuf, DTSUM, Abuf);
    scan_phase3<<<dim3(DI / 256, NC, BATCH), 256, 0, stream>>>(
        XACTB, YLOC, PROJ, Abuf, Dp, Hbuf, XZb);

    // t7) out = y @ W_out.T  (A = y in XZb cols 0..2047, lda = 4096)
    cvt_bf16<<<DMODEL * DI / 8 / 256, 256, 0, stream>>>(W_out, W_outb, DMODEL * DI / 8);
    gemm_bf16_nt<<<dim3(DMODEL / 128, M / 128), 256, 0, stream>>>(
        XZb, 4096, W_outb, DI, out, M, DMODEL, DI);
}

// Round 7
// 211.520 us; speedup vs baseline: 4.8844x; 1.0479x over previous
//
#include <hip/hip_runtime.h>
#include <hip/hip_bf16.h>
#include <cstddef>

#define DMODEL 1024
#define DI     2048
#define DS     16
#define LSEQ   2048
#define BATCH  2
#define NC     128           // number of scan chunks
#define TCH    (LSEQ / NC)   // 16 steps per chunk

typedef __attribute__((ext_vector_type(8))) short short8;
typedef __attribute__((ext_vector_type(4))) float f32x4;
typedef __attribute__((ext_vector_type(2))) float f32x2;
typedef __attribute__((ext_vector_type(8))) unsigned short us8;

__device__ __forceinline__ unsigned short f2bf(float f) {
    unsigned int u = __float_as_uint(f);
    unsigned int r = (u + 0x7fff + ((u >> 16) & 1)) >> 16;   // RNE
    return (unsigned short)r;
}
__device__ __forceinline__ float bf2f(unsigned short b) {
    return __uint_as_float(((unsigned int)b) << 16);
}

__device__ __forceinline__ float fexp2(float x) {
#if __has_builtin(__builtin_amdgcn_exp2f)
    return __builtin_amdgcn_exp2f(x);
#else
    return exp2f(x);
#endif
}
__device__ __forceinline__ float flog2(float x) {
#if __has_builtin(__builtin_amdgcn_logf)
    return __builtin_amdgcn_logf(x);
#else
    return log2f(x);
#endif
}

#define LOG2E 1.4426950408889634f
#define RLOG2E 0.6931471805599453f

__device__ __forceinline__ float softplus_f(float v) {
    return (v > 20.f) ? v : flog2(1.f + fexp2(v * LOG2E)) * RLOG2E;
}

__device__ __forceinline__ void gload_lds16(const void* g, void* l) {
    __builtin_amdgcn_global_load_lds(
        (const __attribute__((address_space(1))) unsigned int*)g,
        (__attribute__((address_space(3))) unsigned int*)l, 16, 0, 0);
}

// ---------------------------------------------------------------------------
// f32 -> bf16 convert
// ---------------------------------------------------------------------------
__global__ void cvt_bf16(const float* __restrict__ in, unsigned short* __restrict__ out, int n8) {
    int i = blockIdx.x * 256 + threadIdx.x;
    if (i >= n8) return;
    const float4* p = reinterpret_cast<const float4*>(in) + i * 2;
    float4 v0 = p[0], v1 = p[1];
    us8 o;
    o[0] = f2bf(v0.x); o[1] = f2bf(v0.y); o[2] = f2bf(v0.z); o[3] = f2bf(v0.w);
    o[4] = f2bf(v1.x); o[5] = f2bf(v1.y); o[6] = f2bf(v1.z); o[7] = f2bf(v1.w);
    *reinterpret_cast<us8*>(out + (size_t)i * 8) = o;
}

// W_x (33x2048 f32) -> bf16 padded to 48 rows
__global__ void prep_wx(const float* __restrict__ wx, unsigned short* __restrict__ out) {
    int i = blockIdx.x * 256 + threadIdx.x;
    if (i >= 48 * 2048 / 8) return;
    size_t o = (size_t)i * 8;
    int row = (int)(o >> 11);
    us8 v;
    if (row < 33) {
        const float4* p = reinterpret_cast<const float4*>(wx + o);
        float4 v0 = p[0], v1 = p[1];
        v[0] = f2bf(v0.x); v[1] = f2bf(v0.y); v[2] = f2bf(v0.z); v[3] = f2bf(v0.w);
        v[4] = f2bf(v1.x); v[5] = f2bf(v1.y); v[6] = f2bf(v1.z); v[7] = f2bf(v1.w);
    } else {
        v = (us8)0;
    }
    *reinterpret_cast<us8*>(out + o) = v;
}

// A table, transposed + log2e-folded
__global__ void prep_A(const float* __restrict__ A_log, float* __restrict__ At2) {
    int i = blockIdx.x * 256 + threadIdx.x;
    if (i >= DS * DI) return;
    int n = i / DI, d = i % DI;
    At2[i] = -__expf(A_log[d * DS + n]) * LOG2E;
}

// ---------------------------------------------------------------------------
// GEMM1: 256x256 tile, 8 waves, BK=32, 4-deep LDS pipeline, counted vmcnt,
// k-unit XOR swizzle, bf16 out.  M=N=4096, K=1024 fixed.
// ---------------------------------------------------------------------------
#define NT1 32
__global__ __launch_bounds__(512, 1)
void gemm1_pipe(const unsigned short* __restrict__ A, const unsigned short* __restrict__ B,
                unsigned short* __restrict__ C) {
    __shared__ unsigned short lds[4][2][256 * 32];   // 128 KiB

    const int tid = threadIdx.x;
    const int wid = tid >> 6, ln = tid & 63;
    const int wm = wid >> 2, wn = wid & 3;           // 2 x 4 waves; wave owns 128x64

    int wg = blockIdx.x;
    wg = (wg & 7) * 32 + (wg >> 3);                  // XCD swizzle (256 % 8 == 0)
    const int m0 = (wg >> 4) * 256;
    const int n0 = (wg & 15) * 256;

    const int srow = tid >> 2;                       // 0..127 staging row
    const int sun  = tid & 3;                        // staging k-unit slot
    const int ksrc = ((sun ^ ((srow >> 1) & 3)) * 8);  // inverse-swizzled source k

    const int fr = ln & 15;
    const int fku = (ln >> 4);                       // frag k-unit 0..3

    f32x4 acc[8][4] = {};

    #define STAGE1(kt)                                                                     \
        do {                                                                               \
            const int bq_ = (kt) & 3;                                                      \
            gload_lds16(A + (size_t)(m0 + srow) * 1024 + (kt) * 32 + ksrc,                 \
                        &lds[bq_][0][srow * 32 + sun * 8]);                                \
            gload_lds16(A + (size_t)(m0 + 128 + srow) * 1024 + (kt) * 32 + ksrc,           \
                        &lds[bq_][0][(128 + srow) * 32 + sun * 8]);                        \
            gload_lds16(B + (size_t)(n0 + srow) * 1024 + (kt) * 32 + ksrc,                 \
                        &lds[bq_][1][srow * 32 + sun * 8]);                                \
            gload_lds16(B + (size_t)(n0 + 128 + srow) * 1024 + (kt) * 32 + ksrc,           \
                        &lds[bq_][1][(128 + srow) * 32 + sun * 8]);                        \
        } while (0)

    STAGE1(0); STAGE1(1); STAGE1(2);
    asm volatile("s_waitcnt vmcnt(8)" ::: "memory");   // K-tile 0 landed
    __builtin_amdgcn_s_barrier();
    __builtin_amdgcn_sched_barrier(0);

    for (int kt = 0; kt < NT1; ++kt) {
        const int bq = kt & 3;
        if (kt + 3 < NT1) STAGE1(kt + 3);            // targets buf[(kt-1)&3]: read-done

        short8 af_lo[4], bfr[4], af_hi[4];
        #pragma unroll
        for (int i = 0; i < 4; ++i) {
            int r = wm * 128 + i * 16 + fr;
            int u = fku ^ ((r >> 1) & 3);
            af_lo[i] = *reinterpret_cast<const short8*>(&lds[bq][0][r * 32 + u * 8]);
        }
        #pragma unroll
        for (int j = 0; j < 4; ++j) {
            int r = wn * 64 + j * 16 + fr;
            int u = fku ^ ((r >> 1) & 3);
            bfr[j] = *reinterpret_cast<const short8*>(&lds[bq][1][r * 32 + u * 8]);
        }
        #pragma unroll
        for (int i = 0; i < 4; ++i) {
            int r = wm * 128 + (4 + i) * 16 + fr;
            int u = fku ^ ((r >> 1) & 3);
            af_hi[i] = *reinterpret_cast<const short8*>(&lds[bq][0][r * 32 + u * 8]);
        }
        __builtin_amdgcn_sched_barrier(0);
        __builtin_amdgcn_s_setprio(1);
        #pragma unroll
        for (int i = 0; i < 4; ++i)
            #pragma unroll
            for (int j = 0; j < 4; ++j)
                acc[i][j] = __builtin_amdgcn_mfma_f32_16x16x32_bf16(af_lo[i], bfr[j], acc[i][j], 0, 0, 0);
        __builtin_amdgcn_s_setprio(0);
        __builtin_amdgcn_sched_barrier(0);
        __builtin_amdgcn_s_setprio(1);
        #pragma unroll
        for (int i = 0; i < 4; ++i)
            #pragma unroll
            for (int j = 0; j < 4; ++j)
                acc[4 + i][j] = __builtin_amdgcn_mfma_f32_16x16x32_bf16(af_hi[i], bfr[j], acc[4 + i][j], 0, 0, 0);
        __builtin_amdgcn_s_setprio(0);
        __builtin_amdgcn_sched_barrier(0);

        if (kt < NT1 - 3)       asm volatile("s_waitcnt vmcnt(8)" ::: "memory");
        else if (kt == NT1 - 3) asm volatile("s_waitcnt vmcnt(4)" ::: "memory");
        else if (kt == NT1 - 2) asm volatile("s_waitcnt vmcnt(0)" ::: "memory");
        __builtin_amdgcn_s_barrier();
        __builtin_amdgcn_sched_barrier(0);
    }
    #undef STAGE1

    const int cr = (ln >> 4) * 4, cc = ln & 15;
    #pragma unroll
    for (int i = 0; i < 8; ++i) {
        int row = m0 + wm * 128 + i * 16 + cr;
        #pragma unroll
        for (int j = 0; j < 4; ++j) {
            int col = n0 + wn * 64 + j * 16 + cc;
            #pragma unroll
            for (int r = 0; r < 4; ++r)
                C[(size_t)(row + r) * 4096 + col] = f2bf(acc[i][j][r]);
        }
    }
}

// ---------------------------------------------------------------------------
// GEMM3: 128x64 tile, 4 waves (2x2), BK=32, 4-deep pipeline, counted vmcnt,
// k-unit XOR swizzle, f32 out.  M=4096, N=1024, K=2048 fixed; grid 512.
// 3 loads/stage/thread (2x A, 1x B) -> steady vmcnt(6), tail 3/0.
// ---------------------------------------------------------------------------
#define NT3 64
__global__ __launch_bounds__(256, 2)
void gemm3_pipe(const unsigned short* __restrict__ A, int lda,
                const unsigned short* __restrict__ B,
                float* __restrict__ C) {
    __shared__ unsigned short As[4][128 * 32];   // 32 KiB
    __shared__ unsigned short Bs[4][64 * 32];    // 16 KiB

    const int tid = threadIdx.x;
    const int wid = tid >> 6, ln = tid & 63;
    const int wm = wid >> 1, wn = wid & 1;       // wave owns 64x32

    int wg = blockIdx.x;
    wg = (wg & 7) * 64 + (wg >> 3);              // XCD swizzle (512 % 8 == 0)
    const int m0 = (wg >> 4) * 128;
    const int n0 = (wg & 15) * 64;

    const int srow = tid >> 2;                   // 0..63
    const int sun  = tid & 3;
    const int ksrc = ((sun ^ ((srow >> 1) & 3)) * 8);   // (r>>1)&3 identical for r and r+64

    const int fr = ln & 15;
    const int fku = (ln >> 4);

    f32x4 acc[4][2] = {};

    #define STAGE3(kt)                                                                     \
        do {                                                                               \
            const int bq_ = (kt) & 3;                                                      \
            gload_lds16(A + (size_t)(m0 + srow) * lda + (kt) * 32 + ksrc,                  \
                        &As[bq_][srow * 32 + sun * 8]);                                    \
            gload_lds16(A + (size_t)(m0 + 64 + srow) * lda + (kt) * 32 + ksrc,             \
                        &As[bq_][(64 + srow) * 32 + sun * 8]);                             \
            gload_lds16(B + (size_t)(n0 + srow) * 2048 + (kt) * 32 + ksrc,                 \
                        &Bs[bq_][srow * 32 + sun * 8]);                                    \
        } while (0)

    STAGE3(0); STAGE3(1); STAGE3(2);
    asm volatile("s_waitcnt vmcnt(6)" ::: "memory");   // K-tile 0 landed
    __builtin_amdgcn_s_barrier();
    __builtin_amdgcn_sched_barrier(0);

    for (int kt = 0; kt < NT3; ++kt) {
        const int bq = kt & 3;
        if (kt + 3 < NT3) STAGE3(kt + 3);

        short8 af[4], bfr[2];
        #pragma unroll
        for (int i = 0; i < 4; ++i) {
            int r = wm * 64 + i * 16 + fr;
            int u = fku ^ ((r >> 1) & 3);
            af[i] = *reinterpret_cast<const short8*>(&As[bq][r * 32 + u * 8]);
        }
        #pragma unroll
        for (int j = 0; j < 2; ++j) {
            int r = wn * 32 + j * 16 + fr;
            int u = fku ^ ((r >> 1) & 3);
            bfr[j] = *reinterpret_cast<const short8*>(&Bs[bq][r * 32 + u * 8]);
        }
        __builtin_amdgcn_sched_barrier(0);
        __builtin_amdgcn_s_setprio(1);
        #pragma unroll
        for (int i = 0; i < 4; ++i)
            #pragma unroll
            for (int j = 0; j < 2; ++j)
                acc[i][j] = __builtin_amdgcn_mfma_f32_16x16x32_bf16(af[i], bfr[j], acc[i][j], 0, 0, 0);
        __builtin_amdgcn_s_setprio(0);
        __builtin_amdgcn_sched_barrier(0);

        if (kt < NT3 - 3)       asm volatile("s_waitcnt vmcnt(6)" ::: "memory");
        else if (kt == NT3 - 3) asm volatile("s_waitcnt vmcnt(3)" ::: "memory");
        else if (kt == NT3 - 2) asm volatile("s_waitcnt vmcnt(0)" ::: "memory");
        __builtin_amdgcn_s_barrier();
        __builtin_amdgcn_sched_barrier(0);
    }
    #undef STAGE3

    const int cr = (ln >> 4) * 4, cc = ln & 15;
    #pragma unroll
    for (int i = 0; i < 4; ++i) {
        int row = m0 + wm * 64 + i * 16 + cr;
        #pragma unroll
        for (int j = 0; j < 2; ++j) {
            int col = n0 + wn * 32 + j * 16 + cc;
            #pragma unroll
            for (int r = 0; r < 4; ++r)
                C[(size_t)(row + r) * 1024 + col] = acc[i][j][r];
        }
    }
}

// ---------------------------------------------------------------------------
// depthwise causal conv (width 4) + bias + SiLU; bf16 in (XZb), bf16 out
// ---------------------------------------------------------------------------
__global__ void conv_silu(const unsigned short* __restrict__ xzb, const float* __restrict__ cw,
                          const float* __restrict__ cb, unsigned short* __restrict__ xactb) {
    int i = blockIdx.x * 256 + threadIdx.x;        // over B*L*DI/8
    if (i >= BATCH * LSEQ * DI / 8) return;
    int d0 = (i % (DI / 8)) * 8;
    int l  = (i / (DI / 8)) % LSEQ;
    int b  = i / ((DI / 8) * LSEQ);

    float4 w[8];
    #pragma unroll
    for (int j = 0; j < 8; ++j)
        w[j] = *reinterpret_cast<const float4*>(cw + (d0 + j) * 4);

    float acc[8];
    #pragma unroll
    for (int j = 0; j < 8; ++j) acc[j] = cb[d0 + j];

    #pragma unroll
    for (int t = 0; t < 4; ++t) {
        int ls = l - 3 + t;
        if (ls >= 0) {
            us8 v = *reinterpret_cast<const us8*>(xzb + (size_t)(b * LSEQ + ls) * 4096 + d0);
            #pragma unroll
            for (int j = 0; j < 8; ++j) {
                float wt = (t == 0) ? w[j].x : (t == 1) ? w[j].y : (t == 2) ? w[j].z : w[j].w;
                acc[j] += bf2f(v[j]) * wt;
            }
        }
    }
    us8 o;
    #pragma unroll
    for (int j = 0; j < 8; ++j) {
        float v = acc[j] / (1.f + __expf(-acc[j]));
        o[j] = f2bf(v);
    }
    *reinterpret_cast<us8*>(xactb + (size_t)i * 8) = o;
}

// ---------------------------------------------------------------------------
// skinny MFMA GEMM for proj: partials -> PROJP[row*144 + kz*36 + col]
// ---------------------------------------------------------------------------
__global__ __launch_bounds__(256)
void gemm_proj_mfma(const unsigned short* __restrict__ Xb, const unsigned short* __restrict__ Wxb,
                    float* __restrict__ projp) {
    __shared__ unsigned short As[64 * 32];
    __shared__ unsigned short Bs[48 * 32];

    const int tid = threadIdx.x;
    const int wv = tid >> 6, ln = tid & 63;
    const int m0 = blockIdx.x * 64;
    const int kz = blockIdx.y;
    const int srow = tid >> 2, skoff = (tid & 3) * 8;
    const int fr = ln & 15, fk = (ln >> 4) * 8;

    f32x4 acc[3] = {};

    const int k0base = kz * 512;
    for (int k0 = k0base; k0 < k0base + 512; k0 += 32) {
        gload_lds16(Xb + (size_t)(m0 + srow) * DI + k0 + skoff, &As[wv * 512]);
        if (wv < 3)
            gload_lds16(Wxb + (size_t)srow * DI + k0 + skoff, &Bs[wv * 512]);
        __syncthreads();

        short8 af = *reinterpret_cast<const short8*>(&As[(wv * 16 + fr) * 32 + fk]);
        #pragma unroll
        for (int j = 0; j < 3; ++j) {
            short8 bf_ = *reinterpret_cast<const short8*>(&Bs[(j * 16 + fr) * 32 + fk]);
            acc[j] = __builtin_amdgcn_mfma_f32_16x16x32_bf16(af, bf_, acc[j], 0, 0, 0);
        }
        __syncthreads();
    }

    const int cr = (ln >> 4) * 4, cc = ln & 15;
    #pragma unroll
    for (int j = 0; j < 3; ++j) {
        int col = j * 16 + cc;
        if (col < 33) {
            #pragma unroll
            for (int r = 0; r < 4; ++r) {
                int row = m0 + wv * 16 + cr + r;
                projp[(size_t)row * 144 + kz * 36 + col] = acc[j][r];
            }
        }
    }
}

// combine 4 K-split partials
__global__ void proj_combine(const float* __restrict__ projp, float* __restrict__ proj) {
    int idx = blockIdx.x * 256 + threadIdx.x;
    if (idx >= BATCH * LSEQ * 33) return;
    int row = idx / 33, col = idx % 33;
    float s = 0.f;
    #pragma unroll
    for (int kz = 0; kz < 4; ++kz)
        s += projp[(size_t)row * 144 + kz * 36 + col];
    proj[(size_t)row * 36 + col] = s;
}

// ---------------------------------------------------------------------------
// scan phase 1: local scan (h0=0); y_local (bf16), S prefix (bf16 into XZb
// x-cols), Hend (bf16), dtsum (f32)
// ---------------------------------------------------------------------------
__global__ __launch_bounds__(256)
void scan_phase1(const unsigned short* __restrict__ xactb, const float* __restrict__ proj,
                 const float* __restrict__ At2, const float* __restrict__ W_dt,
                 const float* __restrict__ b_dt, unsigned short* __restrict__ Hend,
                 float* __restrict__ dtsum, unsigned short* __restrict__ yloc,
                 unsigned short* __restrict__ XZb) {
    const int d = blockIdx.x * 256 + threadIdx.x;
    const int c = blockIdx.y;
    const int b = blockIdx.z;

    f32x2 A2[DS / 2], h2[DS / 2];
    #pragma unroll
    for (int p = 0; p < DS / 2; ++p) {
        A2[p] = (f32x2){At2[(2 * p) * DI + d], At2[(2 * p + 1) * DI + d]};
        h2[p] = (f32x2){0.f, 0.f};
    }
    const float wdt = W_dt[d], bdt = b_dt[d];
    float ssum = 0.f;

    const int l0 = c * TCH;
    #pragma unroll 2
    for (int l = l0; l < l0 + TCH; ++l) {
        const size_t row = (size_t)(b * LSEQ + l);
        const float* pr = proj + row * 36;
        float dt = softplus_f(pr[32] * wdt + bdt);
        ssum += dt;
        XZb[row * 4096 + d] = f2bf(ssum);
        float x = bf2f(xactb[row * DI + d]);
        float xdt = x * dt;
        f32x2 xdt2 = (f32x2){xdt, xdt};
        f32x2 y2 = (f32x2){0.f, 0.f};
        #pragma unroll
        for (int p = 0; p < DS / 2; ++p) {
            f32x2 t = A2[p] * dt;
            f32x2 e2 = (f32x2){fexp2(t.x), fexp2(t.y)};
            h2[p] = e2 * h2[p] + xdt2 * (f32x2){pr[2 * p], pr[2 * p + 1]};
            y2 += h2[p] * (f32x2){pr[16 + 2 * p], pr[17 + 2 * p]};
        }
        yloc[row * DI + d] = f2bf(y2.x + y2.y);
    }
    size_t base = ((size_t)(b * NC + c) * DS) * DI + d;
    #pragma unroll
    for (int p = 0; p < DS / 2; ++p) {
        Hend[base + (size_t)(2 * p) * DI]     = f2bf(h2[p].x);
        Hend[base + (size_t)(2 * p + 1) * DI] = f2bf(h2[p].y);
    }
    dtsum[(size_t)(b * NC + c) * DI + d] = ssum;
}

// ---------------------------------------------------------------------------
// scan phase 2: in-place chunk combine (bf16 H); Hend -> Hin
// ---------------------------------------------------------------------------
__global__ void scan_phase2(unsigned short* __restrict__ H, const float* __restrict__ dtsum,
                            const float* __restrict__ At2) {
    int idx = blockIdx.x * 256 + threadIdx.x;
    int b = idx / (DS * DI);
    int r = idx % (DS * DI);
    int n = r / DI, d = r % DI;
    float A2 = At2[n * DI + d];
    float h = 0.f;
    #pragma unroll 4
    for (int c = 0; c < NC; ++c) {
        size_t off = ((size_t)(b * NC + c) * DS + n) * DI + d;
        float He = bf2f(H[off]);
        float P = fexp2(A2 * dtsum[(size_t)(b * NC + c) * DI + d]);
        H[off] = f2bf(h);
        h = P * h + He;
    }
}

// ---------------------------------------------------------------------------
// scan phase 3: parallel correction + gate; y (bf16) over S slots in XZb
// ---------------------------------------------------------------------------
__global__ __launch_bounds__(256)
void scan_phase3(const unsigned short* __restrict__ xactb, const unsigned short* __restrict__ yloc,
                 const float* __restrict__ proj, const float* __restrict__ At2,
                 const float* __restrict__ Dp, const unsigned short* __restrict__ Hin,
                 unsigned short* __restrict__ XZb) {
    const int tid = threadIdx.x;
    const int d = blockIdx.x * 256 + tid;
    const int c = blockIdx.y;
    const int b = blockIdx.z;

    f32x2 A2[DS / 2], Hn2[DS / 2];
    size_t hbase = ((size_t)(b * NC + c) * DS) * DI + d;
    #pragma unroll
    for (int p = 0; p < DS / 2; ++p) {
        A2[p]  = (f32x2){At2[(2 * p) * DI + d], At2[(2 * p + 1) * DI + d]};
        Hn2[p] = (f32x2){bf2f(Hin[hbase + (size_t)(2 * p) * DI]),
                         bf2f(Hin[hbase + (size_t)(2 * p + 1) * DI])};
    }

    const float Dv = Dp[d];
    const int l0 = c * TCH;
    #pragma unroll 2
    for (int l = l0; l < l0 + TCH; ++l) {
        const size_t row = (size_t)(b * LSEQ + l);
        const float* pr = proj + row * 36;
        unsigned short* xzrow = XZb + row * 4096;
        float S  = bf2f(xzrow[d]);
        float yl = bf2f(yloc[row * DI + d]);
        float x  = bf2f(xactb[row * DI + d]);
        float z  = bf2f(xzrow[2048 + d]);
        f32x2 corr2 = (f32x2){0.f, 0.f};
        #pragma unroll
        for (int p = 0; p < DS / 2; ++p) {
            f32x2 t = A2[p] * S;
            f32x2 e2 = (f32x2){fexp2(t.x), fexp2(t.y)};
            corr2 += (f32x2){pr[16 + 2 * p], pr[17 + 2 * p]} * e2 * Hn2[p];
        }
        float y = yl + corr2.x + corr2.y + x * Dv;
        float sz = z / (1.f + __expf(-z));
        xzrow[d] = f2bf(y * sz);
    }
}

// ---------------------------------------------------------------------------
extern "C" void kernel_launch(void* const* d_in, const int* in_sizes, int n_in,
                              void* d_out, int out_size, void* d_ws, size_t ws_size,
                              hipStream_t stream) {
    const float* x      = (const float*)d_in[0];
    const float* W_in   = (const float*)d_in[1];
    const float* conv_w = (const float*)d_in[2];
    const float* conv_b = (const float*)d_in[3];
    const float* W_x    = (const float*)d_in[4];
    const float* A_log  = (const float*)d_in[5];
    const float* Dp     = (const float*)d_in[6];
    const float* W_dt   = (const float*)d_in[7];
    const float* b_dt   = (const float*)d_in[8];
    const float* W_out  = (const float*)d_in[9];
    float* out = (float*)d_out;

    char* ws = (char*)d_ws;
    // workspace layout (bytes), ~112 MiB, no overlays:
    unsigned short* XZb   = (unsigned short*)(ws + 0);           // 32 MiB  [t1..t7]
    unsigned short* XACTB = (unsigned short*)(ws + 33554432);    // 16 MiB  [t2..t6]
    unsigned short* Xb    = (unsigned short*)(ws + 50331648);    // 8 MiB   [t0..t1]
    unsigned short* W_inb = (unsigned short*)(ws + 58720256);    // 8 MiB   [t0..t1]
    unsigned short* Hbuf  = (unsigned short*)(ws + 67108864);    // 16 MiB  [t4..t6]
    unsigned short* YLOC  = (unsigned short*)(ws + 83886080);    // 16 MiB  [t4..t6]
    float* PROJ  = (float*)(ws + 100663296);                     // 0.56 MiB
    float* DTSUM = (float*)(ws + 101711872);                     // 2 MiB
    float* PROJP = (float*)(ws + 103809024);                     // 2.25 MiB
    float* Abuf  = (float*)(ws + 106954752);                     // 128 KiB
    unsigned short* W_outb = (unsigned short*)(ws + 108003328);  // 4 MiB
    unsigned short* Wxb48  = (unsigned short*)(ws + 112197632);  // 192 KiB

    const int M = BATCH * LSEQ;   // 4096

    // t0) converts / prep
    cvt_bf16<<<M * DMODEL / 8 / 256, 256, 0, stream>>>(x, Xb, M * DMODEL / 8);
    cvt_bf16<<<2 * DI * DMODEL / 8 / 256, 256, 0, stream>>>(W_in, W_inb, 2 * DI * DMODEL / 8);
    prep_wx<<<48, 256, 0, stream>>>(W_x, Wxb48);
    prep_A<<<DS * DI / 256, 256, 0, stream>>>(A_log, Abuf);

    // t1) xz = x @ W_in.T -> bf16 XZb (pipelined 256^2 kernel)
    gemm1_pipe<<<256, 512, 0, stream>>>(Xb, W_inb, XZb);

    // t2) depthwise conv + SiLU -> XACTB (bf16)
    conv_silu<<<BATCH * LSEQ * DI / 8 / 256, 256, 0, stream>>>(XZb, conv_w, conv_b, XACTB);

    // t3) proj
    gemm_proj_mfma<<<dim3(M / 64, 4), 256, 0, stream>>>(XACTB, Wxb48, PROJP);
    proj_combine<<<(M * 33 + 255) / 256, 256, 0, stream>>>(PROJP, PROJ);

    // t4-t6) chunked scan
    scan_phase1<<<dim3(DI / 256, NC, BATCH), 256, 0, stream>>>(
        XACTB, PROJ, Abuf, W_dt, b_dt, Hbuf, DTSUM, YLOC, XZb);
    scan_phase2<<<BATCH * DS * DI / 256, 256, 0, stream>>>(Hbuf, DTSUM, Abuf);
    scan_phase3<<<dim3(DI / 256, NC, BATCH), 256, 0, stream>>>(
        XACTB, YLOC, PROJ, Abuf, Dp, Hbuf, XZb);

    // t7) out = y @ W_out.T  (A = y in XZb cols 0..2047, lda = 4096) -- pipelined
    cvt_bf16<<<DMODEL * DI / 8 / 256, 256, 0, stream>>>(W_out, W_outb, DMODEL * DI / 8);
    gemm3_pipe<<<512, 256, 0, stream>>>(XZb, 4096, W_outb, out);
}